// Round 6
// baseline (609.171 us; speedup 1.0000x reference)
//
#include <hip/hip_runtime.h>
#include <hip/hip_bf16.h>

#define NN 50000
#define EE 500000
#define DIN 64
#define HIDD 128
#define NG 64
#define NB1 49  // ceil(NN/1024) scan blocks

typedef short short8 __attribute__((ext_vector_type(8)));
typedef float f32x4 __attribute__((ext_vector_type(4)));
typedef float f32x2 __attribute__((ext_vector_type(2)));

__device__ __forceinline__ short f2bf(float f) {
  unsigned u = __float_as_uint(f);
  u += 0x7fffu + ((u >> 16) & 1u);  // RNE
  return (short)(u >> 16);
}

struct BiasW { const float* b[4]; };
struct PrepW { const float* w[12]; };

// ---------------- CSR build ----------------
__global__ __launch_bounds__(256) void count_kernel(const int* __restrict__ ei,
                                                    int* __restrict__ cnt, int E) {
  int e = blockIdx.x * 256 + threadIdx.x;
  if (e < E) atomicAdd(&cnt[ei[E + e]], 1);
}

__global__ __launch_bounds__(1024) void scan1_kernel(const int* __restrict__ cnts,
                                                     int* __restrict__ starts,
                                                     int* __restrict__ btot) {
  __shared__ int sh[1024];
  int t = threadIdx.x;
  int idx = blockIdx.x * 1024 + t;
  int v = (idx < NN) ? cnts[idx] : 0;
  sh[t] = v;
  __syncthreads();
  for (int off = 1; off < 1024; off <<= 1) {
    int add = (t >= off) ? sh[t - off] : 0;
    __syncthreads();
    sh[t] += add;
    __syncthreads();
  }
  if (idx < NN) starts[idx] = sh[t] - v;
  if (t == 1023) btot[blockIdx.x] = sh[1023];
}

__global__ __launch_bounds__(64) void scan2_kernel(const int* __restrict__ btot,
                                                   int* __restrict__ boff,
                                                   int* __restrict__ starts) {
  int t = threadIdx.x;
  int orig = (t < NB1) ? btot[t] : 0;
  int v = orig;
  for (int off = 1; off < 64; off <<= 1) {
    int n_ = __shfl_up(v, off);
    if (t >= off) v += n_;
  }
  if (t < NB1) boff[t] = v - orig;
  if (t == NB1 - 1) starts[NN] = v;
}

__global__ __launch_bounds__(256) void scan3_kernel(int* __restrict__ starts,
                                                    const int* __restrict__ boff,
                                                    int* __restrict__ pos) {
  int i = blockIdx.x * 256 + threadIdx.x;
  if (i < NN) {
    int s = starts[i] + boff[i >> 10];
    starts[i] = s;
    pos[i] = s;
  }
}

__global__ __launch_bounds__(256) void scatter_kernel(const int* __restrict__ ei,
                                                      int* __restrict__ pos,
                                                      int* __restrict__ csr_src, int E) {
  int e = blockIdx.x * 256 + threadIdx.x;
  if (e < E) {
    int dst = ei[E + e];
    int p = atomicAdd(&pos[dst], 1);
    csr_src[p] = ei[e];
  }
}

// ---------------- weight prep: transpose + cast to bf16 ----------------
// wT layout: mats 0..3 (l0, K=64): [128][64] at m*8192
//            mats 4..11 (layers, K=128): [128][128] at 32768+(m-4)*16384
__global__ __launch_bounds__(256) void prep_kernel(PrepW pw, short* __restrict__ wT) {
  int o = blockIdx.x * 256 + threadIdx.x;
  if (o >= 163840) return;
  int m, local, K;
  if (o < 32768) { m = o >> 13; local = o & 8191; K = 64; }
  else { int oo = o - 32768; m = 4 + (oo >> 14); local = oo & 16383; K = 128; }
  int n = (K == 64) ? (local >> 6) : (local >> 7);
  int k = local & (K - 1);
  wT[o] = f2bf(__builtin_nontemporal_load(&pw.w[m][(size_t)k * 128 + n]));
}

// ---------------- bf16 MFMA GEMM: h[N,K] x W[K,128], 4 mats fused ----------------
// 256 threads = 4 waves = 2 row-groups x 2 col-halves; 32 rows/block; grid ceil(N/32).
// NT loads/stores keep the streaming h/qf/sf/kvb out of L2 so wT stays L2-resident.
// Full-batch register prefetch of B fragments (16 loads in flight per mat).
// mat 0 -> Q (f32), 1 -> K (bf16 kv[:,0:128]), 2 -> V (bf16 kv[:,128:256]), 3 -> S (f32)
template <int K>
__global__ __launch_bounds__(256, 4) void gemm_qkvs(
    const float* __restrict__ h, const short* __restrict__ wT, BiasW bw,
    float* __restrict__ qf, unsigned short* __restrict__ kvb,
    float* __restrict__ sf, int N) {
  __shared__ short aS[32 * K];
  constexpr int SLOTS = K / 8;
  constexpr int RB = 2 * K;
  const int n0 = blockIdx.x * 32;
  const int t = threadIdx.x;

  // stage A tile (32 x K): f32 -> bf16 (NT loads), XOR-swizzled rows
  for (int idx = t; idx < 32 * SLOTS; idx += 256) {
    int row = idx / SLOTS, slot = idx % SLOTS;
    int gr = n0 + row;
    f32x4 f0 = {0.f, 0.f, 0.f, 0.f}, f1 = f0;
    if (gr < N) {
      const float* hp = &h[(size_t)gr * K + slot * 8];
      f0 = __builtin_nontemporal_load((const f32x4*)hp);
      f1 = __builtin_nontemporal_load((const f32x4*)(hp + 4));
    }
    short8 pk;
    pk[0] = f2bf(f0.x); pk[1] = f2bf(f0.y); pk[2] = f2bf(f0.z); pk[3] = f2bf(f0.w);
    pk[4] = f2bf(f1.x); pk[5] = f2bf(f1.y); pk[6] = f2bf(f1.z); pk[7] = f2bf(f1.w);
    unsigned byte = row * RB + ((slot * 16) ^ ((row & 7) << 4));
    *(short8*)((char*)aS + byte) = pk;
  }
  __syncthreads();

  const int l = t & 63, wv = t >> 6;       // 4 waves
  const int lr = l & 15, lk = l >> 4;
  const int rowg = wv >> 1;                // 2 row-groups of 16
  const int colbase = (wv & 1) * 64;       // 2 col-halves
  const int arow = rowg * 16 + lr;

  short8 afrag[K / 32];
#pragma unroll
  for (int ks = 0; ks < K / 32; ++ks) {
    unsigned ab = arow * RB + ((((ks * 4 + lk) * 16)) ^ ((arow & 7) << 4));
    afrag[ks] = *(const short8*)((const char*)aS + ab);
  }

#pragma unroll
  for (int mat = 0; mat < 4; ++mat) {
    const short* __restrict__ w = wT + (size_t)mat * 128 * K;
    // batch-prefetch ALL B fragments for this mat into registers (L2-resident)
    short8 bf[(K / 32) * 4];
#pragma unroll
    for (int ks = 0; ks < K / 32; ++ks)
#pragma unroll
      for (int cf = 0; cf < 4; ++cf)
        bf[ks * 4 + cf] =
            *(const short8*)&w[(size_t)(colbase + cf * 16 + lr) * K + ks * 32 + lk * 8];

    f32x4 acc[4] = {};
#pragma unroll
    for (int ks = 0; ks < K / 32; ++ks)
#pragma unroll
      for (int cf = 0; cf < 4; ++cf)
        acc[cf] = __builtin_amdgcn_mfma_f32_16x16x32_bf16(afrag[ks], bf[ks * 4 + cf],
                                                          acc[cf], 0, 0, 0);

    const float* __restrict__ bias = bw.b[mat];
#pragma unroll
    for (int cf = 0; cf < 4; ++cf) {
      int col = colbase + cf * 16 + lr;
      float bv = bias[col];
#pragma unroll
      for (int r = 0; r < 4; ++r) {
        int row = n0 + rowg * 16 + lk * 4 + r;
        if (row < N) {
          float val = acc[cf][r] + bv;
          if (mat == 0)
            __builtin_nontemporal_store(val, &qf[(size_t)row * 128 + col]);
          else if (mat == 3)
            __builtin_nontemporal_store(val, &sf[(size_t)row * 128 + col]);
          else
            __builtin_nontemporal_store(
                (unsigned short)f2bf(val),
                &kvb[(size_t)row * 256 + (mat == 2 ? 128 : 0) + col]);
        }
      }
    }
  }
}

// ---------------- fused attention + beta gate + LN + GELU ----------------
// one wave per node. lanes 0-31 own K-side (4 channels each), lanes 32-63 own
// V-side/output. ONE uint2 (8B) gather per edge per lane (512B row coverage).
__global__ __launch_bounds__(256, 8) void attn_fused(
    const float* __restrict__ qf, const unsigned* __restrict__ kvu,
    const float* __restrict__ sf, const int* __restrict__ starts,
    const int* __restrict__ csr, const float* __restrict__ Wbeta,
    const float* __restrict__ lng, const float* __restrict__ lnb,
    float* __restrict__ hout, int N) {
  int wid = (blockIdx.x * 256 + threadIdx.x) >> 6;
  if (wid >= N) return;
  const int lane = threadIdx.x & 63;
  const int cl = lane & 31;  // channel group: channels 4*cl .. 4*cl+3
  const float scale = 0.17677669529663687f;  // 1/sqrt(32)
  f32x4 q4 = __builtin_nontemporal_load((const f32x4*)&qf[(size_t)wid * 128 + 4 * cl]);
  q4.x *= scale; q4.y *= scale; q4.z *= scale; q4.w *= scale;
  int s0 = starts[wid], s1 = starts[wid + 1];
  float d = 0.f, ox = 0.f, oy = 0.f, oz = 0.f, ow = 0.f;
  for (int i = s0; i < s1; i += 8) {
    int src[8];
#pragma unroll
    for (int e = 0; e < 8; ++e) {
      int idx = i + e;
      idx = (idx < s1) ? idx : (s1 - 1);
      src[e] = csr[idx];
    }
    uint2 wv2[8];
#pragma unroll
    for (int e = 0; e < 8; ++e)
      wv2[e] = *(const uint2*)&kvu[(size_t)src[e] * 128 + 2 * lane];
#pragma unroll
    for (int e = 0; e < 8; ++e) {
      float fx = __uint_as_float(wv2[e].x << 16);
      float fy = __uint_as_float(wv2[e].x & 0xffff0000u);
      float fz = __uint_as_float(wv2[e].y << 16);
      float fw = __uint_as_float(wv2[e].y & 0xffff0000u);
      float part = q4.x * fx + q4.y * fy + q4.z * fz + q4.w * fw;
      part += __shfl_xor(part, 1);
      part += __shfl_xor(part, 2);
      part += __shfl_xor(part, 4);  // head-sum over 8 lanes
      float p = __expf(part);
      p = (i + e < s1) ? p : 0.f;
      float pm = __shfl(p, cl);  // broadcast head-p to matching V lane
      d += p;                    // meaningful in lanes 0-31
      ox = fmaf(pm, fx, ox); oy = fmaf(pm, fy, oy);  // meaningful in lanes 32-63
      oz = fmaf(pm, fz, oz); ow = fmaf(pm, fw, ow);
    }
  }
  float dv = __shfl(d, cl);
  float inv = dv > 0.f ? 1.f / dv : 0.f;
  ox *= inv; oy *= inv; oz *= inv; ow *= inv;
  f32x4 sv4 = __builtin_nontemporal_load((const f32x4*)&sf[(size_t)wid * 128 + 4 * cl]);
  f32x4 wbo = *(const f32x4*)&Wbeta[4 * cl];
  f32x4 wbx = *(const f32x4*)&Wbeta[128 + 4 * cl];
  f32x4 wbd = *(const f32x4*)&Wbeta[256 + 4 * cl];
  float bl = ox * wbo.x + oy * wbo.y + oz * wbo.z + ow * wbo.w
           + sv4.x * wbx.x + sv4.y * wbx.y + sv4.z * wbx.z + sv4.w * wbx.w
           + (ox - sv4.x) * wbd.x + (oy - sv4.y) * wbd.y
           + (oz - sv4.z) * wbd.z + (ow - sv4.w) * wbd.w;
  bl += __shfl_xor(bl, 1);  bl += __shfl_xor(bl, 2);  bl += __shfl_xor(bl, 4);
  bl += __shfl_xor(bl, 8);  bl += __shfl_xor(bl, 16);  // sum over 32-lane half
  float beta = 1.f / (1.f + __expf(-bl));
  float hx = beta * sv4.x + (1.f - beta) * ox;
  float hy = beta * sv4.y + (1.f - beta) * oy;
  float hz = beta * sv4.z + (1.f - beta) * oz;
  float hw = beta * sv4.w + (1.f - beta) * ow;
  float s = hx + hy + hz + hw;
  float sq = hx * hx + hy * hy + hz * hz + hw * hw;
  s += __shfl_xor(s, 1);  sq += __shfl_xor(sq, 1);
  s += __shfl_xor(s, 2);  sq += __shfl_xor(sq, 2);
  s += __shfl_xor(s, 4);  sq += __shfl_xor(sq, 4);
  s += __shfl_xor(s, 8);  sq += __shfl_xor(sq, 8);
  s += __shfl_xor(s, 16); sq += __shfl_xor(sq, 16);
  float mu = s * (1.f / 128.f);
  float var = sq * (1.f / 128.f) - mu * mu;
  float rstd = 1.f / sqrtf(var + 1e-5f);
  f32x4 g4 = *(const f32x4*)&lng[4 * cl];
  f32x4 b4 = *(const f32x4*)&lnb[4 * cl];
  float y0 = (hx - mu) * rstd * g4.x + b4.x;
  float y1 = (hy - mu) * rstd * g4.y + b4.y;
  float y2 = (hz - mu) * rstd * g4.z + b4.z;
  float y3 = (hw - mu) * rstd * g4.w + b4.w;
  y0 = 0.5f * y0 * (1.f + erff(y0 * 0.70710678118654752f));
  y1 = 0.5f * y1 * (1.f + erff(y1 * 0.70710678118654752f));
  y2 = 0.5f * y2 * (1.f + erff(y2 * 0.70710678118654752f));
  y3 = 0.5f * y3 * (1.f + erff(y3 * 0.70710678118654752f));
  if (lane >= 32) {
    f32x4 o = {y0, y1, y2, y3};
    __builtin_nontemporal_store(o, (f32x4*)&hout[(size_t)wid * 128 + 4 * cl]);
  }
}

// ---------------- mean pool ----------------
__global__ __launch_bounds__(256) void pool_kernel(const float* __restrict__ h,
    const int* __restrict__ batch, float* __restrict__ g,
    float* __restrict__ gcnt, int N) {
  __shared__ float accS[NG * HIDD];
  __shared__ float cntS[NG];
  int t = threadIdx.x;
  for (int i = t; i < NG * HIDD; i += 256) accS[i] = 0.f;
  if (t < NG) cntS[t] = 0.f;
  __syncthreads();
  int lane = t & 63, grp = t >> 6;
  for (int n = blockIdx.x * 4 + grp; n < N; n += gridDim.x * 4) {
    int b = batch[n];
    f32x2 hv = __builtin_nontemporal_load(
        (const f32x2*)&h[(size_t)n * HIDD + (lane << 1)]);
    atomicAdd(&accS[b * HIDD + (lane << 1)], hv.x);
    atomicAdd(&accS[b * HIDD + (lane << 1) + 1], hv.y);
    if (lane == 0) atomicAdd(&cntS[b], 1.f);
  }
  __syncthreads();
  for (int i = t; i < NG * HIDD; i += 256)
    if (accS[i] != 0.f) atomicAdd(&g[i], accS[i]);
  if (t < NG && cntS[t] != 0.f) atomicAdd(&gcnt[t], cntS[t]);
}

// ---------------- final MLP (single block) ----------------
__global__ __launch_bounds__(256) void final_kernel(const float* __restrict__ g,
    const float* __restrict__ gcnt, const float* __restrict__ W1,
    const float* __restrict__ b1, const float* __restrict__ W2,
    const float* __restrict__ b2, float* __restrict__ out) {
  __shared__ float gS[NG * HIDD];
  __shared__ float hmS[NG * HIDD];
  int t = threadIdx.x;
  for (int i = t; i < NG * HIDD; i += 256) {
    int gr = i >> 7;
    gS[i] = g[i] / fmaxf(gcnt[gr], 1.f);
  }
  __syncthreads();
  for (int i = t; i < NG * HIDD; i += 256) {
    int gr = i >> 7, col = i & 127;
    float s = b1[col];
    for (int k = 0; k < HIDD; ++k) s = fmaf(gS[gr * HIDD + k], W1[k * HIDD + col], s);
    hmS[i] = 0.5f * s * (1.f + erff(s * 0.70710678118654752f));
  }
  __syncthreads();
  if (t < NG) {
    float s = b2[0];
    for (int k = 0; k < HIDD; ++k) s = fmaf(hmS[t * HIDD + k], W2[k], s);
    out[t] = s;
  }
}

extern "C" void kernel_launch(void* const* d_in, const int* in_sizes, int n_in,
                              void* d_out, int out_size, void* d_ws, size_t ws_size,
                              hipStream_t stream) {
  const float* x        = (const float*)d_in[0];
  const int*   ei       = (const int*)d_in[1];
  const int*   batch    = (const int*)d_in[2];
  const float* l0_Wq    = (const float*)d_in[3];
  const float* l0_bq    = (const float*)d_in[4];
  const float* l0_Wk    = (const float*)d_in[5];
  const float* l0_bk    = (const float*)d_in[6];
  const float* l0_Wv    = (const float*)d_in[7];
  const float* l0_bv    = (const float*)d_in[8];
  const float* l0_Ws    = (const float*)d_in[9];
  const float* l0_bs    = (const float*)d_in[10];
  const float* l0_Wbeta = (const float*)d_in[11];
  const float* l0_lng   = (const float*)d_in[12];
  const float* l0_lnb   = (const float*)d_in[13];
  const float* Wq       = (const float*)d_in[14];
  const float* bq       = (const float*)d_in[15];
  const float* Wk       = (const float*)d_in[16];
  const float* bk       = (const float*)d_in[17];
  const float* Wv       = (const float*)d_in[18];
  const float* bv       = (const float*)d_in[19];
  const float* Ws       = (const float*)d_in[20];
  const float* bs       = (const float*)d_in[21];
  const float* Wbeta    = (const float*)d_in[22];
  const float* lng      = (const float*)d_in[23];
  const float* lnb      = (const float*)d_in[24];
  const float* mlp_W1   = (const float*)d_in[25];
  const float* mlp_b1   = (const float*)d_in[26];
  const float* mlp_W2   = (const float*)d_in[27];
  const float* mlp_b2   = (const float*)d_in[28];
  float* outp = (float*)d_out;

  char* ws = (char*)d_ws;
  size_t off = 0;
  auto alloc = [&](size_t bytes) -> void* {
    void* p = ws + off;
    off = (off + bytes + 255) & ~(size_t)255;
    return p;
  };
  float*  h0     = (float*)alloc((size_t)NN * HIDD * 4);
  float*  h1     = (float*)alloc((size_t)NN * HIDD * 4);
  float*  qf     = (float*)alloc((size_t)NN * HIDD * 4);
  float*  sf     = (float*)alloc((size_t)NN * HIDD * 4);
  unsigned short* kvb = (unsigned short*)alloc((size_t)NN * 256 * 2);
  short*  wT     = (short*)alloc((size_t)163840 * 2);
  int*    starts = (int*)alloc((size_t)(NN + 1) * 4);
  int*    pos    = (int*)alloc((size_t)NN * 4);
  int*    csr    = (int*)alloc((size_t)EE * 4);
  int*    btot   = (int*)alloc((size_t)NB1 * 4);
  int*    boff   = (int*)alloc((size_t)NB1 * 4);
  float*  g      = (float*)alloc((size_t)NG * HIDD * 4);
  float*  gcnt   = (float*)alloc((size_t)NG * 4);
  (void)ws_size; (void)in_sizes; (void)n_in; (void)out_size;

  // ---- weight prep (transpose + bf16 cast) ----
  PrepW pw = {{l0_Wq, l0_Wk, l0_Wv, l0_Ws,
               Wq, Wk, Wv, Ws,
               Wq + 16384, Wk + 16384, Wv + 16384, Ws + 16384}};
  prep_kernel<<<640, 256, 0, stream>>>(pw, wT);

  // ---- CSR build (by dst) ----
  hipMemsetAsync(pos, 0, (size_t)NN * 4, stream);
  count_kernel<<<(EE + 255) / 256, 256, 0, stream>>>(ei, pos, EE);
  scan1_kernel<<<NB1, 1024, 0, stream>>>(pos, starts, btot);
  scan2_kernel<<<1, 64, 0, stream>>>(btot, boff, starts);
  scan3_kernel<<<(NN + 255) / 256, 256, 0, stream>>>(starts, boff, pos);
  scatter_kernel<<<(EE + 255) / 256, 256, 0, stream>>>(ei, pos, csr, EE);

  int ggrid = (NN + 31) / 32;
  int agrid = (NN + 3) / 4;
  const unsigned* kvu = (const unsigned*)kvb;

  // ---- layer 0 (64 -> 128) ----
  BiasW b0 = {{l0_bq, l0_bk, l0_bv, l0_bs}};
  gemm_qkvs<DIN><<<ggrid, 256, 0, stream>>>(x, wT, b0, qf, kvb, sf, NN);
  attn_fused<<<agrid, 256, 0, stream>>>(qf, kvu, sf, starts, csr, l0_Wbeta,
                                        l0_lng, l0_lnb, h0, NN);

  // ---- layer 1 ----
  BiasW b1s = {{bq, bk, bv, bs}};
  gemm_qkvs<HIDD><<<ggrid, 256, 0, stream>>>(h0, wT + 32768, b1s, qf, kvb, sf, NN);
  attn_fused<<<agrid, 256, 0, stream>>>(qf, kvu, sf, starts, csr, Wbeta,
                                        lng, lnb, h1, NN);

  // ---- layer 2 ----
  BiasW b2s = {{bq + HIDD, bk + HIDD, bv + HIDD, bs + HIDD}};
  gemm_qkvs<HIDD><<<ggrid, 256, 0, stream>>>(h1, wT + 98304, b2s, qf, kvb, sf, NN);
  attn_fused<<<agrid, 256, 0, stream>>>(qf, kvu, sf, starts, csr, Wbeta + 384,
                                        lng + HIDD, lnb + HIDD, h0, NN);

  // ---- pool + MLP ----
  hipMemsetAsync(g, 0, (size_t)NG * HIDD * 4, stream);
  hipMemsetAsync(gcnt, 0, (size_t)NG * 4, stream);
  pool_kernel<<<256, 256, 0, stream>>>(h0, batch, g, gcnt, NN);
  final_kernel<<<1, 256, 0, stream>>>(g, gcnt, mlp_W1, mlp_b1, mlp_W2, mlp_b2, outp);
}

// Round 7
// 505.893 us; speedup vs baseline: 1.2041x; 1.2041x over previous
//
#include <hip/hip_runtime.h>
#include <hip/hip_bf16.h>

#define NN 50000
#define EE 500000
#define DIN 64
#define HIDD 128
#define NG 64
#define NB1 49  // ceil(NN/1024) scan blocks

typedef short short8 __attribute__((ext_vector_type(8)));
typedef float f32x4 __attribute__((ext_vector_type(4)));

// async global->LDS, 16B per lane; LDS dest = wave-uniform base + lane*16
#define GLL(g, l)                                                              \
  __builtin_amdgcn_global_load_lds(                                            \
      (const __attribute__((address_space(1))) unsigned*)(g),                  \
      (__attribute__((address_space(3))) unsigned*)(l), 16, 0, 0)

__device__ __forceinline__ short f2bf(float f) {
  unsigned u = __float_as_uint(f);
  u += 0x7fffu + ((u >> 16) & 1u);  // RNE
  return (short)(u >> 16);
}
__device__ __forceinline__ float bfl(unsigned short u) {
  return __uint_as_float((unsigned)u << 16);
}

struct BiasW { const float* b[4]; };
struct PrepW { const float* w[12]; };

// ---------------- CSR build ----------------
__global__ __launch_bounds__(256) void count_kernel(const int* __restrict__ ei,
                                                    int* __restrict__ cnt, int E) {
  int e = blockIdx.x * 256 + threadIdx.x;
  if (e < E) atomicAdd(&cnt[ei[E + e]], 1);
}

__global__ __launch_bounds__(1024) void scan1_kernel(const int* __restrict__ cnts,
                                                     int* __restrict__ starts,
                                                     int* __restrict__ btot) {
  __shared__ int sh[1024];
  int t = threadIdx.x;
  int idx = blockIdx.x * 1024 + t;
  int v = (idx < NN) ? cnts[idx] : 0;
  sh[t] = v;
  __syncthreads();
  for (int off = 1; off < 1024; off <<= 1) {
    int add = (t >= off) ? sh[t - off] : 0;
    __syncthreads();
    sh[t] += add;
    __syncthreads();
  }
  if (idx < NN) starts[idx] = sh[t] - v;
  if (t == 1023) btot[blockIdx.x] = sh[1023];
}

__global__ __launch_bounds__(64) void scan2_kernel(const int* __restrict__ btot,
                                                   int* __restrict__ boff,
                                                   int* __restrict__ starts) {
  int t = threadIdx.x;
  int orig = (t < NB1) ? btot[t] : 0;
  int v = orig;
  for (int off = 1; off < 64; off <<= 1) {
    int n_ = __shfl_up(v, off);
    if (t >= off) v += n_;
  }
  if (t < NB1) boff[t] = v - orig;
  if (t == NB1 - 1) starts[NN] = v;
}

__global__ __launch_bounds__(256) void scan3_kernel(int* __restrict__ starts,
                                                    const int* __restrict__ boff,
                                                    int* __restrict__ pos) {
  int i = blockIdx.x * 256 + threadIdx.x;
  if (i < NN) {
    int s = starts[i] + boff[i >> 10];
    starts[i] = s;
    pos[i] = s;
  }
}

__global__ __launch_bounds__(256) void scatter_kernel(const int* __restrict__ ei,
                                                      int* __restrict__ pos,
                                                      int* __restrict__ csr_src, int E) {
  int e = blockIdx.x * 256 + threadIdx.x;
  if (e < E) {
    int dst = ei[E + e];
    int p = atomicAdd(&pos[dst], 1);
    csr_src[p] = ei[e];
  }
}

// ---------------- weight prep: transpose + bf16 + PRE-SWIZZLE ----------------
// Stored so a LINEAR global_load_lds copy yields the XOR-swizzled LDS image:
//   LDSbyte[col*RB + (slot*16 ^ ((col&7)<<4)) + 2j] = W[slot*8+j][col]
// mats 0..3 (l0, K=64, RB=128): at m*8192 shorts
// mats 4..11 (K=128, RB=256): at 32768+(m-4)*16384 shorts
__global__ __launch_bounds__(256) void prep_kernel(PrepW pw, short* __restrict__ wT) {
  int o = blockIdx.x * 256 + threadIdx.x;
  if (o >= 163840) return;
  int m, local, K;
  if (o < 32768) { m = o >> 13; local = o & 8191; K = 64; }
  else { int oo = o - 32768; m = 4 + (oo >> 14); local = oo & 16383; K = 128; }
  int col = local / K;
  int off = (local % K) * 2;              // byte offset within col
  int sw = off ^ ((col & 7) << 4);        // un-swizzle (XOR hits bits 4-6 only)
  int k = (sw >> 4) * 8 + ((sw & 15) >> 1);
  wT[o] = f2bf(pw.w[m][(size_t)k * 128 + col]);
}

// ---------------- bf16 MFMA GEMM: h[N,K] x W[K,128], 4 mats fused ----------------
// 64 rows/block, 256 threads = 4 waves (16 rows x 128 cols each); grid ceil(N/64).
// B staged to LDS via async global_load_lds from pre-swizzled wT, double-buffered
// across the mat loop. All outputs bf16.
// mat 0 -> Q, 1 -> K (kv[:,0:128]), 2 -> V (kv[:,128:256]), 3 -> S
template <int K, bool BF16IN>
__global__ __launch_bounds__(256) void gemm_qkvs(
    const void* __restrict__ hin, const short* __restrict__ wT, BiasW bw,
    unsigned short* __restrict__ qb, unsigned short* __restrict__ kvb,
    unsigned short* __restrict__ sb, int N) {
  constexpr int RB = 2 * K;
  constexpr int SLOTS = K / 8;
  constexpr int BCALLS = (128 * RB) / 4096;
  __shared__ short aS[64 * K];
  __shared__ short bS[2][128 * K];
  const int n0 = blockIdx.x * 64;
  const int t = threadIdx.x;
  const int l = t & 63, wv = t >> 6;

  // async-stage B for mat 0
  {
    const char* g0 = (const char*)wT;
    char* l0p = (char*)&bS[0][0];
#pragma unroll
    for (int i = 0; i < BCALLS; ++i)
      GLL(g0 + i * 4096 + wv * 1024 + l * 16, l0p + i * 4096 + wv * 1024);
  }

  // stage A (64 x K) -> bf16, XOR-swizzled rows
  for (int idx = t; idx < 64 * SLOTS; idx += 256) {
    int row = idx / SLOTS, slot = idx % SLOTS;
    int gr = n0 + row;
    short8 pk = {0, 0, 0, 0, 0, 0, 0, 0};
    if (BF16IN) {
      if (gr < N)
        pk = *(const short8*)((const short*)hin + (size_t)gr * K + slot * 8);
    } else {
      if (gr < N) {
        const float* hp = (const float*)hin + (size_t)gr * K + slot * 8;
        f32x4 f0 = *(const f32x4*)hp;
        f32x4 f1 = *(const f32x4*)(hp + 4);
        pk[0] = f2bf(f0.x); pk[1] = f2bf(f0.y); pk[2] = f2bf(f0.z); pk[3] = f2bf(f0.w);
        pk[4] = f2bf(f1.x); pk[5] = f2bf(f1.y); pk[6] = f2bf(f1.z); pk[7] = f2bf(f1.w);
      }
    }
    unsigned byte = row * RB + ((slot * 16) ^ ((row & 7) << 4));
    *(short8*)((char*)aS + byte) = pk;
  }
  __syncthreads();  // A visible; B0 landed (compiler drains vmcnt at barrier)

  const int lr = l & 15, lk = l >> 4;
  const int arow = wv * 16 + lr;
  short8 afrag[K / 32];
#pragma unroll
  for (int ks = 0; ks < K / 32; ++ks) {
    unsigned ab = arow * RB + ((((ks * 4 + lk) * 16)) ^ ((arow & 7) << 4));
    afrag[ks] = *(const short8*)((const char*)aS + ab);
  }

  int cur = 0;
#pragma unroll
  for (int mat = 0; mat < 4; ++mat) {
    // issue next mat's async stage into the other buffer (overlaps MFMA phase)
    if (mat < 3) {
      const char* gm = (const char*)(wT + (size_t)(mat + 1) * 128 * K);
      char* lm = (char*)&bS[cur ^ 1][0];
#pragma unroll
      for (int i = 0; i < BCALLS; ++i)
        GLL(gm + i * 4096 + wv * 1024 + l * 16, lm + i * 4096 + wv * 1024);
    }

    f32x4 acc[8] = {};
    const char* bbase = (const char*)&bS[cur][0];
#pragma unroll
    for (int ks = 0; ks < K / 32; ++ks) {
#pragma unroll
      for (int cf = 0; cf < 8; ++cf) {
        int col = cf * 16 + lr;
        unsigned bb = col * RB + ((((ks * 4 + lk) * 16)) ^ ((col & 7) << 4));
        short8 b = *(const short8*)(bbase + bb);
        acc[cf] = __builtin_amdgcn_mfma_f32_16x16x32_bf16(afrag[ks], b, acc[cf], 0, 0, 0);
      }
    }

    const float* __restrict__ bias = bw.b[mat];
#pragma unroll
    for (int cf = 0; cf < 8; ++cf) {
      int col = cf * 16 + lr;
      float bv = bias[col];
#pragma unroll
      for (int r = 0; r < 4; ++r) {
        int row = n0 + wv * 16 + lk * 4 + r;
        if (row < N) {
          unsigned short val = (unsigned short)f2bf(acc[cf][r] + bv);
          if (mat == 0) qb[(size_t)row * 128 + col] = val;
          else if (mat == 3) sb[(size_t)row * 128 + col] = val;
          else kvb[(size_t)row * 256 + (mat == 2 ? 128 : 0) + col] = val;
        }
      }
    }
    __syncthreads();  // next buffer landed; safe to overwrite cur next iter
    cur ^= 1;
  }
}

// ---------------- fused attention + beta gate + LN + GELU ----------------
// one wave per node. lanes 0-31 own K-side (4 channels each), lanes 32-63 own
// V-side/output. ONE uint2 (8B) gather per edge per lane (512B row coverage).
__global__ __launch_bounds__(256, 8) void attn_fused(
    const unsigned short* __restrict__ qb, const unsigned* __restrict__ kvu,
    const unsigned short* __restrict__ sb, const int* __restrict__ starts,
    const int* __restrict__ csr, const float* __restrict__ Wbeta,
    const float* __restrict__ lng, const float* __restrict__ lnb,
    unsigned short* __restrict__ hout, int N) {
  int wid = (blockIdx.x * 256 + threadIdx.x) >> 6;
  if (wid >= N) return;
  const int lane = threadIdx.x & 63;
  const int cl = lane & 31;  // channel group: channels 4*cl .. 4*cl+3
  const float scale = 0.17677669529663687f;  // 1/sqrt(32)
  ushort4 qu = *(const ushort4*)&qb[(size_t)wid * 128 + 4 * cl];
  float qx = bfl(qu.x) * scale, qy = bfl(qu.y) * scale;
  float qz = bfl(qu.z) * scale, qw = bfl(qu.w) * scale;
  int s0 = starts[wid], s1 = starts[wid + 1];
  float d = 0.f, ox = 0.f, oy = 0.f, oz = 0.f, ow = 0.f;
  for (int i = s0; i < s1; i += 8) {
    int src[8];
#pragma unroll
    for (int e = 0; e < 8; ++e) {
      int idx = i + e;
      idx = (idx < s1) ? idx : (s1 - 1);
      src[e] = csr[idx];
    }
    uint2 wv2[8];
#pragma unroll
    for (int e = 0; e < 8; ++e)
      wv2[e] = *(const uint2*)&kvu[(size_t)src[e] * 128 + 2 * lane];
#pragma unroll
    for (int e = 0; e < 8; ++e) {
      float fx = __uint_as_float(wv2[e].x << 16);
      float fy = __uint_as_float(wv2[e].x & 0xffff0000u);
      float fz = __uint_as_float(wv2[e].y << 16);
      float fw = __uint_as_float(wv2[e].y & 0xffff0000u);
      float part = qx * fx + qy * fy + qz * fz + qw * fw;
      part += __shfl_xor(part, 1);
      part += __shfl_xor(part, 2);
      part += __shfl_xor(part, 4);  // head-sum over 8 lanes
      float p = __expf(part);
      p = (i + e < s1) ? p : 0.f;
      float pm = __shfl(p, cl);  // broadcast head-p to matching V lane
      d += p;                    // meaningful in lanes 0-31
      ox = fmaf(pm, fx, ox); oy = fmaf(pm, fy, oy);  // meaningful in lanes 32-63
      oz = fmaf(pm, fz, oz); ow = fmaf(pm, fw, ow);
    }
  }
  float dv = __shfl(d, cl);
  float inv = dv > 0.f ? 1.f / dv : 0.f;
  ox *= inv; oy *= inv; oz *= inv; ow *= inv;
  ushort4 su = *(const ushort4*)&sb[(size_t)wid * 128 + 4 * cl];
  float s_x = bfl(su.x), s_y = bfl(su.y), s_z = bfl(su.z), s_w = bfl(su.w);
  f32x4 wbo = *(const f32x4*)&Wbeta[4 * cl];
  f32x4 wbx = *(const f32x4*)&Wbeta[128 + 4 * cl];
  f32x4 wbd = *(const f32x4*)&Wbeta[256 + 4 * cl];
  float bl = ox * wbo.x + oy * wbo.y + oz * wbo.z + ow * wbo.w
           + s_x * wbx.x + s_y * wbx.y + s_z * wbx.z + s_w * wbx.w
           + (ox - s_x) * wbd.x + (oy - s_y) * wbd.y
           + (oz - s_z) * wbd.z + (ow - s_w) * wbd.w;
  bl += __shfl_xor(bl, 1);  bl += __shfl_xor(bl, 2);  bl += __shfl_xor(bl, 4);
  bl += __shfl_xor(bl, 8);  bl += __shfl_xor(bl, 16);  // sum over 32-lane half
  float beta = 1.f / (1.f + __expf(-bl));
  float hx = beta * s_x + (1.f - beta) * ox;
  float hy = beta * s_y + (1.f - beta) * oy;
  float hz = beta * s_z + (1.f - beta) * oz;
  float hw = beta * s_w + (1.f - beta) * ow;
  float s = hx + hy + hz + hw;
  float sq = hx * hx + hy * hy + hz * hz + hw * hw;
  s += __shfl_xor(s, 1);  sq += __shfl_xor(sq, 1);
  s += __shfl_xor(s, 2);  sq += __shfl_xor(sq, 2);
  s += __shfl_xor(s, 4);  sq += __shfl_xor(sq, 4);
  s += __shfl_xor(s, 8);  sq += __shfl_xor(sq, 8);
  s += __shfl_xor(s, 16); sq += __shfl_xor(sq, 16);
  float mu = s * (1.f / 128.f);
  float var = sq * (1.f / 128.f) - mu * mu;
  float rstd = 1.f / sqrtf(var + 1e-5f);
  f32x4 g4 = *(const f32x4*)&lng[4 * cl];
  f32x4 b4 = *(const f32x4*)&lnb[4 * cl];
  float y0 = (hx - mu) * rstd * g4.x + b4.x;
  float y1 = (hy - mu) * rstd * g4.y + b4.y;
  float y2 = (hz - mu) * rstd * g4.z + b4.z;
  float y3 = (hw - mu) * rstd * g4.w + b4.w;
  y0 = 0.5f * y0 * (1.f + erff(y0 * 0.70710678118654752f));
  y1 = 0.5f * y1 * (1.f + erff(y1 * 0.70710678118654752f));
  y2 = 0.5f * y2 * (1.f + erff(y2 * 0.70710678118654752f));
  y3 = 0.5f * y3 * (1.f + erff(y3 * 0.70710678118654752f));
  if (lane >= 32) {
    ushort4 o;
    o.x = (unsigned short)f2bf(y0); o.y = (unsigned short)f2bf(y1);
    o.z = (unsigned short)f2bf(y2); o.w = (unsigned short)f2bf(y3);
    *(ushort4*)&hout[(size_t)wid * 128 + 4 * cl] = o;
  }
}

// ---------------- mean pool (bf16 h input) ----------------
__global__ __launch_bounds__(256) void pool_kernel(const unsigned short* __restrict__ h,
    const int* __restrict__ batch, float* __restrict__ g,
    float* __restrict__ gcnt, int N) {
  __shared__ float accS[NG * HIDD];
  __shared__ float cntS[NG];
  int t = threadIdx.x;
  for (int i = t; i < NG * HIDD; i += 256) accS[i] = 0.f;
  if (t < NG) cntS[t] = 0.f;
  __syncthreads();
  int lane = t & 63, grp = t >> 6;
  const unsigned* h32 = (const unsigned*)h;
  for (int n = blockIdx.x * 4 + grp; n < N; n += gridDim.x * 4) {
    int b = batch[n];
    unsigned u = h32[(size_t)n * 64 + lane];
    atomicAdd(&accS[b * HIDD + (lane << 1)], __uint_as_float(u << 16));
    atomicAdd(&accS[b * HIDD + (lane << 1) + 1], __uint_as_float(u & 0xffff0000u));
    if (lane == 0) atomicAdd(&cntS[b], 1.f);
  }
  __syncthreads();
  for (int i = t; i < NG * HIDD; i += 256)
    if (accS[i] != 0.f) atomicAdd(&g[i], accS[i]);
  if (t < NG && cntS[t] != 0.f) atomicAdd(&gcnt[t], cntS[t]);
}

// ---------------- final MLP (single block) ----------------
__global__ __launch_bounds__(256) void final_kernel(const float* __restrict__ g,
    const float* __restrict__ gcnt, const float* __restrict__ W1,
    const float* __restrict__ b1, const float* __restrict__ W2,
    const float* __restrict__ b2, float* __restrict__ out) {
  __shared__ float gS[NG * HIDD];
  __shared__ float hmS[NG * HIDD];
  int t = threadIdx.x;
  for (int i = t; i < NG * HIDD; i += 256) {
    int gr = i >> 7;
    gS[i] = g[i] / fmaxf(gcnt[gr], 1.f);
  }
  __syncthreads();
  for (int i = t; i < NG * HIDD; i += 256) {
    int gr = i >> 7, col = i & 127;
    float s = b1[col];
    for (int k = 0; k < HIDD; ++k) s = fmaf(gS[gr * HIDD + k], W1[k * HIDD + col], s);
    hmS[i] = 0.5f * s * (1.f + erff(s * 0.70710678118654752f));
  }
  __syncthreads();
  if (t < NG) {
    float s = b2[0];
    for (int k = 0; k < HIDD; ++k) s = fmaf(hmS[t * HIDD + k], W2[k], s);
    out[t] = s;
  }
}

extern "C" void kernel_launch(void* const* d_in, const int* in_sizes, int n_in,
                              void* d_out, int out_size, void* d_ws, size_t ws_size,
                              hipStream_t stream) {
  const float* x        = (const float*)d_in[0];
  const int*   ei       = (const int*)d_in[1];
  const int*   batch    = (const int*)d_in[2];
  const float* l0_Wq    = (const float*)d_in[3];
  const float* l0_bq    = (const float*)d_in[4];
  const float* l0_Wk    = (const float*)d_in[5];
  const float* l0_bk    = (const float*)d_in[6];
  const float* l0_Wv    = (const float*)d_in[7];
  const float* l0_bv    = (const float*)d_in[8];
  const float* l0_Ws    = (const float*)d_in[9];
  const float* l0_bs    = (const float*)d_in[10];
  const float* l0_Wbeta = (const float*)d_in[11];
  const float* l0_lng   = (const float*)d_in[12];
  const float* l0_lnb   = (const float*)d_in[13];
  const float* Wq       = (const float*)d_in[14];
  const float* bq       = (const float*)d_in[15];
  const float* Wk       = (const float*)d_in[16];
  const float* bk       = (const float*)d_in[17];
  const float* Wv       = (const float*)d_in[18];
  const float* bv       = (const float*)d_in[19];
  const float* Ws       = (const float*)d_in[20];
  const float* bs       = (const float*)d_in[21];
  const float* Wbeta    = (const float*)d_in[22];
  const float* lng      = (const float*)d_in[23];
  const float* lnb      = (const float*)d_in[24];
  const float* mlp_W1   = (const float*)d_in[25];
  const float* mlp_b1   = (const float*)d_in[26];
  const float* mlp_W2   = (const float*)d_in[27];
  const float* mlp_b2   = (const float*)d_in[28];
  float* outp = (float*)d_out;

  char* ws = (char*)d_ws;
  size_t off = 0;
  auto alloc = [&](size_t bytes) -> void* {
    void* p = ws + off;
    off = (off + bytes + 255) & ~(size_t)255;
    return p;
  };
  unsigned short* h0  = (unsigned short*)alloc((size_t)NN * HIDD * 2);
  unsigned short* h1  = (unsigned short*)alloc((size_t)NN * HIDD * 2);
  unsigned short* qbv = (unsigned short*)alloc((size_t)NN * HIDD * 2);
  unsigned short* sbv = (unsigned short*)alloc((size_t)NN * HIDD * 2);
  unsigned short* kvb = (unsigned short*)alloc((size_t)NN * 256 * 2);
  short*  wT     = (short*)alloc((size_t)163840 * 2);
  int*    starts = (int*)alloc((size_t)(NN + 1) * 4);
  int*    pos    = (int*)alloc((size_t)NN * 4);
  int*    csr    = (int*)alloc((size_t)EE * 4);
  int*    btot   = (int*)alloc((size_t)NB1 * 4);
  int*    boff   = (int*)alloc((size_t)NB1 * 4);
  float*  g      = (float*)alloc((size_t)NG * HIDD * 4);
  float*  gcnt   = (float*)alloc((size_t)NG * 4);
  (void)ws_size; (void)in_sizes; (void)n_in; (void)out_size;

  // ---- weight prep (transpose + bf16 + pre-swizzle) ----
  PrepW pw = {{l0_Wq, l0_Wk, l0_Wv, l0_Ws,
               Wq, Wk, Wv, Ws,
               Wq + 16384, Wk + 16384, Wv + 16384, Ws + 16384}};
  prep_kernel<<<640, 256, 0, stream>>>(pw, wT);

  // ---- CSR build (by dst) ----
  hipMemsetAsync(pos, 0, (size_t)NN * 4, stream);
  count_kernel<<<(EE + 255) / 256, 256, 0, stream>>>(ei, pos, EE);
  scan1_kernel<<<NB1, 1024, 0, stream>>>(pos, starts, btot);
  scan2_kernel<<<1, 64, 0, stream>>>(btot, boff, starts);
  scan3_kernel<<<(NN + 255) / 256, 256, 0, stream>>>(starts, boff, pos);
  scatter_kernel<<<(EE + 255) / 256, 256, 0, stream>>>(ei, pos, csr, EE);

  int ggrid = (NN + 63) / 64;
  int agrid = (NN + 3) / 4;
  const unsigned* kvu = (const unsigned*)kvb;

  // ---- layer 0 (64 -> 128, f32 input) ----
  BiasW b0 = {{l0_bq, l0_bk, l0_bv, l0_bs}};
  gemm_qkvs<DIN, false><<<ggrid, 256, 0, stream>>>(x, wT, b0, qbv, kvb, sbv, NN);
  attn_fused<<<agrid, 256, 0, stream>>>(qbv, kvu, sbv, starts, csr, l0_Wbeta,
                                        l0_lng, l0_lnb, h0, NN);

  // ---- layer 1 ----
  BiasW b1s = {{bq, bk, bv, bs}};
  gemm_qkvs<HIDD, true><<<ggrid, 256, 0, stream>>>(h0, wT + 32768, b1s, qbv, kvb, sbv, NN);
  attn_fused<<<agrid, 256, 0, stream>>>(qbv, kvu, sbv, starts, csr, Wbeta,
                                        lng, lnb, h1, NN);

  // ---- layer 2 ----
  BiasW b2s = {{bq + HIDD, bk + HIDD, bv + HIDD, bs + HIDD}};
  gemm_qkvs<HIDD, true><<<ggrid, 256, 0, stream>>>(h1, wT + 98304, b2s, qbv, kvb, sbv, NN);
  attn_fused<<<agrid, 256, 0, stream>>>(qbv, kvu, sbv, starts, csr, Wbeta + 384,
                                        lng + HIDD, lnb + HIDD, h0, NN);

  // ---- pool + MLP ----
  hipMemsetAsync(g, 0, (size_t)NG * HIDD * 4, stream);
  hipMemsetAsync(gcnt, 0, (size_t)NG * 4, stream);
  pool_kernel<<<256, 256, 0, stream>>>(h0, batch, g, gcnt, NN);
  final_kernel<<<1, 256, 0, stream>>>(g, gcnt, mlp_W1, mlp_b1, mlp_W2, mlp_b2, outp);
}

// Round 8
// 446.063 us; speedup vs baseline: 1.3657x; 1.1341x over previous
//
#include <hip/hip_runtime.h>
#include <hip/hip_bf16.h>

#define NN 50000
#define EE 500000
#define DIN 64
#define HIDD 128
#define NG 64
#define NB1 49  // ceil(NN/1024) scan blocks

typedef short short8 __attribute__((ext_vector_type(8)));
typedef float f32x4 __attribute__((ext_vector_type(4)));

// async global->LDS, 16B per lane; LDS dest = wave-uniform base + lane*16
#define GLL(g, l)                                                              \
  __builtin_amdgcn_global_load_lds(                                            \
      (const __attribute__((address_space(1))) unsigned*)(g),                  \
      (__attribute__((address_space(3))) unsigned*)(l), 16, 0, 0)

__device__ __forceinline__ short f2bf(float f) {
  unsigned u = __float_as_uint(f);
  u += 0x7fffu + ((u >> 16) & 1u);  // RNE
  return (short)(u >> 16);
}
__device__ __forceinline__ float bfl(unsigned short u) {
  return __uint_as_float((unsigned)u << 16);
}

struct BiasW { const float* b[4]; };
struct PrepW { const float* w[12]; };

// ---------------- CSR build ----------------
__global__ __launch_bounds__(256) void count_kernel(const int* __restrict__ ei,
                                                    int* __restrict__ cnt, int E) {
  int e = blockIdx.x * 256 + threadIdx.x;
  if (e < E) atomicAdd(&cnt[ei[E + e]], 1);
}

__global__ __launch_bounds__(1024) void scan1_kernel(const int* __restrict__ cnts,
                                                     int* __restrict__ starts,
                                                     int* __restrict__ btot) {
  __shared__ int sh[1024];
  int t = threadIdx.x;
  int idx = blockIdx.x * 1024 + t;
  int v = (idx < NN) ? cnts[idx] : 0;
  sh[t] = v;
  __syncthreads();
  for (int off = 1; off < 1024; off <<= 1) {
    int add = (t >= off) ? sh[t - off] : 0;
    __syncthreads();
    sh[t] += add;
    __syncthreads();
  }
  if (idx < NN) starts[idx] = sh[t] - v;
  if (t == 1023) btot[blockIdx.x] = sh[1023];
}

__global__ __launch_bounds__(64) void scan2_kernel(const int* __restrict__ btot,
                                                   int* __restrict__ boff,
                                                   int* __restrict__ starts) {
  int t = threadIdx.x;
  int orig = (t < NB1) ? btot[t] : 0;
  int v = orig;
  for (int off = 1; off < 64; off <<= 1) {
    int n_ = __shfl_up(v, off);
    if (t >= off) v += n_;
  }
  if (t < NB1) boff[t] = v - orig;
  if (t == NB1 - 1) starts[NN] = v;
}

__global__ __launch_bounds__(256) void scan3_kernel(int* __restrict__ starts,
                                                    const int* __restrict__ boff,
                                                    int* __restrict__ pos) {
  int i = blockIdx.x * 256 + threadIdx.x;
  if (i < NN) {
    int s = starts[i] + boff[i >> 10];
    starts[i] = s;
    pos[i] = s;
  }
}

__global__ __launch_bounds__(256) void scatter_kernel(const int* __restrict__ ei,
                                                      int* __restrict__ pos,
                                                      int* __restrict__ csr_src, int E) {
  int e = blockIdx.x * 256 + threadIdx.x;
  if (e < 8) csr_src[E + e] = 0;  // zero pad so tail batches can overread safely
  if (e < E) {
    int dst = ei[E + e];
    int p = atomicAdd(&pos[dst], 1);
    csr_src[p] = ei[e];
  }
}

// ---------------- weight prep: transpose + bf16 + PRE-SWIZZLE ----------------
// Stored so a LINEAR global_load_lds copy yields the XOR-swizzled LDS image:
//   LDSbyte[col*RB + (slot*16 ^ ((col&7)<<4)) + 2j] = W[slot*8+j][col]
__global__ __launch_bounds__(256) void prep_kernel(PrepW pw, short* __restrict__ wT) {
  int o = blockIdx.x * 256 + threadIdx.x;
  if (o >= 163840) return;
  int m, local, K;
  if (o < 32768) { m = o >> 13; local = o & 8191; K = 64; }
  else { int oo = o - 32768; m = 4 + (oo >> 14); local = oo & 16383; K = 128; }
  int col = local / K;
  int off = (local % K) * 2;              // byte offset within col
  int sw = off ^ ((col & 7) << 4);        // un-swizzle (XOR hits bits 4-6 only)
  int k = (sw >> 4) * 8 + ((sw & 15) >> 1);
  wT[o] = f2bf(pw.w[m][(size_t)k * 128 + col]);
}

// ---------------- bf16 MFMA GEMM: h[N,K] x W[K,128], 4 mats fused ----------------
// 64 rows/block, 256 threads = 4 waves (16 rows x 128 cols each); grid ceil(N/64).
// B staged to LDS via async global_load_lds from pre-swizzled wT, double-buffered.
template <int K, bool BF16IN>
__global__ __launch_bounds__(256) void gemm_qkvs(
    const void* __restrict__ hin, const short* __restrict__ wT, BiasW bw,
    unsigned short* __restrict__ qb, unsigned short* __restrict__ kvb,
    unsigned short* __restrict__ sb, int N) {
  constexpr int RB = 2 * K;
  constexpr int SLOTS = K / 8;
  constexpr int BCALLS = (128 * RB) / 4096;
  __shared__ short aS[64 * K];
  __shared__ short bS[2][128 * K];
  const int n0 = blockIdx.x * 64;
  const int t = threadIdx.x;
  const int l = t & 63, wv = t >> 6;

  // async-stage B for mat 0
  {
    const char* g0 = (const char*)wT;
    char* l0p = (char*)&bS[0][0];
#pragma unroll
    for (int i = 0; i < BCALLS; ++i)
      GLL(g0 + i * 4096 + wv * 1024 + l * 16, l0p + i * 4096 + wv * 1024);
  }

  // stage A (64 x K) -> bf16, XOR-swizzled rows
  for (int idx = t; idx < 64 * SLOTS; idx += 256) {
    int row = idx / SLOTS, slot = idx % SLOTS;
    int gr = n0 + row;
    short8 pk = {0, 0, 0, 0, 0, 0, 0, 0};
    if (BF16IN) {
      if (gr < N)
        pk = *(const short8*)((const short*)hin + (size_t)gr * K + slot * 8);
    } else {
      if (gr < N) {
        const float* hp = (const float*)hin + (size_t)gr * K + slot * 8;
        f32x4 f0 = *(const f32x4*)hp;
        f32x4 f1 = *(const f32x4*)(hp + 4);
        pk[0] = f2bf(f0.x); pk[1] = f2bf(f0.y); pk[2] = f2bf(f0.z); pk[3] = f2bf(f0.w);
        pk[4] = f2bf(f1.x); pk[5] = f2bf(f1.y); pk[6] = f2bf(f1.z); pk[7] = f2bf(f1.w);
      }
    }
    unsigned byte = row * RB + ((slot * 16) ^ ((row & 7) << 4));
    *(short8*)((char*)aS + byte) = pk;
  }
  __syncthreads();  // A visible; B0 landed

  const int lr = l & 15, lk = l >> 4;
  const int arow = wv * 16 + lr;
  short8 afrag[K / 32];
#pragma unroll
  for (int ks = 0; ks < K / 32; ++ks) {
    unsigned ab = arow * RB + ((((ks * 4 + lk) * 16)) ^ ((arow & 7) << 4));
    afrag[ks] = *(const short8*)((const char*)aS + ab);
  }

  int cur = 0;
#pragma unroll
  for (int mat = 0; mat < 4; ++mat) {
    if (mat < 3) {
      const char* gm = (const char*)(wT + (size_t)(mat + 1) * 128 * K);
      char* lm = (char*)&bS[cur ^ 1][0];
#pragma unroll
      for (int i = 0; i < BCALLS; ++i)
        GLL(gm + i * 4096 + wv * 1024 + l * 16, lm + i * 4096 + wv * 1024);
    }

    f32x4 acc[8] = {};
    const char* bbase = (const char*)&bS[cur][0];
#pragma unroll
    for (int ks = 0; ks < K / 32; ++ks) {
#pragma unroll
      for (int cf = 0; cf < 8; ++cf) {
        int col = cf * 16 + lr;
        unsigned bb = col * RB + ((((ks * 4 + lk) * 16)) ^ ((col & 7) << 4));
        short8 b = *(const short8*)(bbase + bb);
        acc[cf] = __builtin_amdgcn_mfma_f32_16x16x32_bf16(afrag[ks], b, acc[cf], 0, 0, 0);
      }
    }

    const float* __restrict__ bias = bw.b[mat];
#pragma unroll
    for (int cf = 0; cf < 8; ++cf) {
      int col = cf * 16 + lr;
      float bv = bias[col];
#pragma unroll
      for (int r = 0; r < 4; ++r) {
        int row = n0 + wv * 16 + lk * 4 + r;
        if (row < N) {
          unsigned short val = (unsigned short)f2bf(acc[cf][r] + bv);
          if (mat == 0) qb[(size_t)row * 128 + col] = val;
          else if (mat == 3) sb[(size_t)row * 128 + col] = val;
          else kvb[(size_t)row * 256 + (mat == 2 ? 128 : 0) + col] = val;
        }
      }
    }
    __syncthreads();
    cur ^= 1;
  }
}

// ---------------- attention edge batch (scalarized gather base) ----------------
// One coalesced csr load (NB entries in lanes 0..NB-1), readlane -> SGPR base per
// edge. Lanes 0-31 compute K-dot+softmax; lanes 32-63 receive p via xor-32 and
// accumulate V. Lower-half accumulators are garbage and never read.
template <int NB, bool MASK>
__device__ __forceinline__ void att_batch(
    const int* __restrict__ csr, int i, int s1, const unsigned* __restrict__ kvu,
    int lane, float qx, float qy, float qz, float qw,
    float& d, float& ox, float& oy, float& oz, float& ow) {
  int ce = csr[i + (lane & (NB - 1))];
  uint2 w[NB];
#pragma unroll
  for (int e = 0; e < NB; ++e) {
    int s = __builtin_amdgcn_readlane(ce, e);  // wave-uniform src -> SGPR
    w[e] = *((const uint2*)kvu + ((size_t)s << 6) + lane);
  }
#pragma unroll
  for (int e = 0; e < NB; ++e) {
    float fx = __uint_as_float(w[e].x << 16);
    float fy = __uint_as_float(w[e].x & 0xffff0000u);
    float fz = __uint_as_float(w[e].y << 16);
    float fw = __uint_as_float(w[e].y & 0xffff0000u);
    float part = qx * fx + qy * fy + qz * fz + qw * fw;
    part += __shfl_xor(part, 1);
    part += __shfl_xor(part, 2);
    part += __shfl_xor(part, 4);  // head-sum over 8 lanes
    float p = __expf(part);
    if (MASK) p = (i + e < s1) ? p : 0.f;
    float pm = __shfl_xor(p, 32);  // upper half <- lower half's p
    d += p;                        // valid in lanes 0-31
    ox = fmaf(pm, fx, ox); oy = fmaf(pm, fy, oy);  // valid in lanes 32-63
    oz = fmaf(pm, fz, oz); ow = fmaf(pm, fw, ow);
  }
}

// ---------------- fused attention + beta gate + LN + GELU ----------------
__global__ __launch_bounds__(256, 8) void attn_fused(
    const unsigned short* __restrict__ qb, const unsigned* __restrict__ kvu,
    const unsigned short* __restrict__ sb, const int* __restrict__ starts,
    const int* __restrict__ csr, const float* __restrict__ Wbeta,
    const float* __restrict__ lng, const float* __restrict__ lnb,
    unsigned short* __restrict__ hout, int N) {
  int wid = (blockIdx.x * 256 + threadIdx.x) >> 6;
  if (wid >= N) return;
  const int lane = threadIdx.x & 63;
  const int cl = lane & 31;  // channel group: channels 4*cl .. 4*cl+3
  const float scale = 0.17677669529663687f;  // 1/sqrt(32)
  ushort4 qu = *(const ushort4*)&qb[(size_t)wid * 128 + 4 * cl];
  float qx = bfl(qu.x) * scale, qy = bfl(qu.y) * scale;
  float qz = bfl(qu.z) * scale, qw = bfl(qu.w) * scale;
  int s0 = starts[wid], s1 = starts[wid + 1];
  float d = 0.f, ox = 0.f, oy = 0.f, oz = 0.f, ow = 0.f;
  int i = s0;
  for (; i + 8 <= s1; i += 8)
    att_batch<8, false>(csr, i, s1, kvu, lane, qx, qy, qz, qw, d, ox, oy, oz, ow);
  if (i < s1) {
    if (s1 - i <= 4)
      att_batch<4, true>(csr, i, s1, kvu, lane, qx, qy, qz, qw, d, ox, oy, oz, ow);
    else
      att_batch<8, true>(csr, i, s1, kvu, lane, qx, qy, qz, qw, d, ox, oy, oz, ow);
  }
  float dv = __shfl_xor(d, 32);  // upper lanes: true denominator
  float inv = dv > 0.f ? 1.f / dv : 0.f;
  ox *= inv; oy *= inv; oz *= inv; ow *= inv;
  ushort4 su = *(const ushort4*)&sb[(size_t)wid * 128 + 4 * cl];
  float s_x = bfl(su.x), s_y = bfl(su.y), s_z = bfl(su.z), s_w = bfl(su.w);
  f32x4 wbo = *(const f32x4*)&Wbeta[4 * cl];
  f32x4 wbx = *(const f32x4*)&Wbeta[128 + 4 * cl];
  f32x4 wbd = *(const f32x4*)&Wbeta[256 + 4 * cl];
  float bl = ox * wbo.x + oy * wbo.y + oz * wbo.z + ow * wbo.w
           + s_x * wbx.x + s_y * wbx.y + s_z * wbx.z + s_w * wbx.w
           + (ox - s_x) * wbd.x + (oy - s_y) * wbd.y
           + (oz - s_z) * wbd.z + (ow - s_w) * wbd.w;
  bl += __shfl_xor(bl, 1);  bl += __shfl_xor(bl, 2);  bl += __shfl_xor(bl, 4);
  bl += __shfl_xor(bl, 8);  bl += __shfl_xor(bl, 16);  // sum within 32-lane half
  float beta = 1.f / (1.f + __expf(-bl));
  float hx = beta * s_x + (1.f - beta) * ox;
  float hy = beta * s_y + (1.f - beta) * oy;
  float hz = beta * s_z + (1.f - beta) * oz;
  float hw = beta * s_w + (1.f - beta) * ow;
  float s = hx + hy + hz + hw;
  float sq = hx * hx + hy * hy + hz * hz + hw * hw;
  s += __shfl_xor(s, 1);  sq += __shfl_xor(sq, 1);
  s += __shfl_xor(s, 2);  sq += __shfl_xor(sq, 2);
  s += __shfl_xor(s, 4);  sq += __shfl_xor(sq, 4);
  s += __shfl_xor(s, 8);  sq += __shfl_xor(sq, 8);
  s += __shfl_xor(s, 16); sq += __shfl_xor(sq, 16);
  float mu = s * (1.f / 128.f);
  float var = sq * (1.f / 128.f) - mu * mu;
  float rstd = 1.f / sqrtf(var + 1e-5f);
  f32x4 g4 = *(const f32x4*)&lng[4 * cl];
  f32x4 b4 = *(const f32x4*)&lnb[4 * cl];
  float y0 = (hx - mu) * rstd * g4.x + b4.x;
  float y1 = (hy - mu) * rstd * g4.y + b4.y;
  float y2 = (hz - mu) * rstd * g4.z + b4.z;
  float y3 = (hw - mu) * rstd * g4.w + b4.w;
  y0 = 0.5f * y0 * (1.f + erff(y0 * 0.70710678118654752f));
  y1 = 0.5f * y1 * (1.f + erff(y1 * 0.70710678118654752f));
  y2 = 0.5f * y2 * (1.f + erff(y2 * 0.70710678118654752f));
  y3 = 0.5f * y3 * (1.f + erff(y3 * 0.70710678118654752f));
  if (lane >= 32) {
    ushort4 o;
    o.x = (unsigned short)f2bf(y0); o.y = (unsigned short)f2bf(y1);
    o.z = (unsigned short)f2bf(y2); o.w = (unsigned short)f2bf(y3);
    *(ushort4*)&hout[(size_t)wid * 128 + 4 * cl] = o;
  }
}

// ---------------- mean pool (bf16 h input) ----------------
__global__ __launch_bounds__(256) void pool_kernel(const unsigned short* __restrict__ h,
    const int* __restrict__ batch, float* __restrict__ g,
    float* __restrict__ gcnt, int N) {
  __shared__ float accS[NG * HIDD];
  __shared__ float cntS[NG];
  int t = threadIdx.x;
  for (int i = t; i < NG * HIDD; i += 256) accS[i] = 0.f;
  if (t < NG) cntS[t] = 0.f;
  __syncthreads();
  int lane = t & 63, grp = t >> 6;
  const unsigned* h32 = (const unsigned*)h;
  for (int n = blockIdx.x * 4 + grp; n < N; n += gridDim.x * 4) {
    int b = batch[n];
    unsigned u = h32[(size_t)n * 64 + lane];
    atomicAdd(&accS[b * HIDD + (lane << 1)], __uint_as_float(u << 16));
    atomicAdd(&accS[b * HIDD + (lane << 1) + 1], __uint_as_float(u & 0xffff0000u));
    if (lane == 0) atomicAdd(&cntS[b], 1.f);
  }
  __syncthreads();
  for (int i = t; i < NG * HIDD; i += 256)
    if (accS[i] != 0.f) atomicAdd(&g[i], accS[i]);
  if (t < NG && cntS[t] != 0.f) atomicAdd(&gcnt[t], cntS[t]);
}

// ---------------- final MLP (single block) ----------------
__global__ __launch_bounds__(256) void final_kernel(const float* __restrict__ g,
    const float* __restrict__ gcnt, const float* __restrict__ W1,
    const float* __restrict__ b1, const float* __restrict__ W2,
    const float* __restrict__ b2, float* __restrict__ out) {
  __shared__ float gS[NG * HIDD];
  __shared__ float hmS[NG * HIDD];
  int t = threadIdx.x;
  for (int i = t; i < NG * HIDD; i += 256) {
    int gr = i >> 7;
    gS[i] = g[i] / fmaxf(gcnt[gr], 1.f);
  }
  __syncthreads();
  for (int i = t; i < NG * HIDD; i += 256) {
    int gr = i >> 7, col = i & 127;
    float s = b1[col];
    for (int k = 0; k < HIDD; ++k) s = fmaf(gS[gr * HIDD + k], W1[k * HIDD + col], s);
    hmS[i] = 0.5f * s * (1.f + erff(s * 0.70710678118654752f));
  }
  __syncthreads();
  if (t < NG) {
    float s = b2[0];
    for (int k = 0; k < HIDD; ++k) s = fmaf(hmS[t * HIDD + k], W2[k], s);
    out[t] = s;
  }
}

extern "C" void kernel_launch(void* const* d_in, const int* in_sizes, int n_in,
                              void* d_out, int out_size, void* d_ws, size_t ws_size,
                              hipStream_t stream) {
  const float* x        = (const float*)d_in[0];
  const int*   ei       = (const int*)d_in[1];
  const int*   batch    = (const int*)d_in[2];
  const float* l0_Wq    = (const float*)d_in[3];
  const float* l0_bq    = (const float*)d_in[4];
  const float* l0_Wk    = (const float*)d_in[5];
  const float* l0_bk    = (const float*)d_in[6];
  const float* l0_Wv    = (const float*)d_in[7];
  const float* l0_bv    = (const float*)d_in[8];
  const float* l0_Ws    = (const float*)d_in[9];
  const float* l0_bs    = (const float*)d_in[10];
  const float* l0_Wbeta = (const float*)d_in[11];
  const float* l0_lng   = (const float*)d_in[12];
  const float* l0_lnb   = (const float*)d_in[13];
  const float* Wq       = (const float*)d_in[14];
  const float* bq       = (const float*)d_in[15];
  const float* Wk       = (const float*)d_in[16];
  const float* bk       = (const float*)d_in[17];
  const float* Wv       = (const float*)d_in[18];
  const float* bv       = (const float*)d_in[19];
  const float* Ws       = (const float*)d_in[20];
  const float* bs       = (const float*)d_in[21];
  const float* Wbeta    = (const float*)d_in[22];
  const float* lng      = (const float*)d_in[23];
  const float* lnb      = (const float*)d_in[24];
  const float* mlp_W1   = (const float*)d_in[25];
  const float* mlp_b1   = (const float*)d_in[26];
  const float* mlp_W2   = (const float*)d_in[27];
  const float* mlp_b2   = (const float*)d_in[28];
  float* outp = (float*)d_out;

  char* ws = (char*)d_ws;
  size_t off = 0;
  auto alloc = [&](size_t bytes) -> void* {
    void* p = ws + off;
    off = (off + bytes + 255) & ~(size_t)255;
    return p;
  };
  unsigned short* h0  = (unsigned short*)alloc((size_t)NN * HIDD * 2);
  unsigned short* h1  = (unsigned short*)alloc((size_t)NN * HIDD * 2);
  unsigned short* qbv = (unsigned short*)alloc((size_t)NN * HIDD * 2);
  unsigned short* sbv = (unsigned short*)alloc((size_t)NN * HIDD * 2);
  unsigned short* kvb = (unsigned short*)alloc((size_t)NN * 256 * 2);
  short*  wT     = (short*)alloc((size_t)163840 * 2);
  int*    starts = (int*)alloc((size_t)(NN + 1) * 4);
  int*    pos    = (int*)alloc((size_t)NN * 4);
  int*    csr    = (int*)alloc((size_t)(EE + 8) * 4);
  int*    btot   = (int*)alloc((size_t)NB1 * 4);
  int*    boff   = (int*)alloc((size_t)NB1 * 4);
  float*  g      = (float*)alloc((size_t)NG * HIDD * 4);
  float*  gcnt   = (float*)alloc((size_t)NG * 4);
  (void)ws_size; (void)in_sizes; (void)n_in; (void)out_size;

  // ---- weight prep (transpose + bf16 + pre-swizzle) ----
  PrepW pw = {{l0_Wq, l0_Wk, l0_Wv, l0_Ws,
               Wq, Wk, Wv, Ws,
               Wq + 16384, Wk + 16384, Wv + 16384, Ws + 16384}};
  prep_kernel<<<640, 256, 0, stream>>>(pw, wT);

  // ---- CSR build (by dst) ----
  hipMemsetAsync(pos, 0, (size_t)NN * 4, stream);
  count_kernel<<<(EE + 255) / 256, 256, 0, stream>>>(ei, pos, EE);
  scan1_kernel<<<NB1, 1024, 0, stream>>>(pos, starts, btot);
  scan2_kernel<<<1, 64, 0, stream>>>(btot, boff, starts);
  scan3_kernel<<<(NN + 255) / 256, 256, 0, stream>>>(starts, boff, pos);
  scatter_kernel<<<(EE + 255) / 256, 256, 0, stream>>>(ei, pos, csr, EE);

  int ggrid = (NN + 63) / 64;
  int agrid = (NN + 3) / 4;
  const unsigned* kvu = (const unsigned*)kvb;

  // ---- layer 0 (64 -> 128, f32 input) ----
  BiasW b0 = {{l0_bq, l0_bk, l0_bv, l0_bs}};
  gemm_qkvs<DIN, false><<<ggrid, 256, 0, stream>>>(x, wT, b0, qbv, kvb, sbv, NN);
  attn_fused<<<agrid, 256, 0, stream>>>(qbv, kvu, sbv, starts, csr, l0_Wbeta,
                                        l0_lng, l0_lnb, h0, NN);

  // ---- layer 1 ----
  BiasW b1s = {{bq, bk, bv, bs}};
  gemm_qkvs<HIDD, true><<<ggrid, 256, 0, stream>>>(h0, wT + 32768, b1s, qbv, kvb, sbv, NN);
  attn_fused<<<agrid, 256, 0, stream>>>(qbv, kvu, sbv, starts, csr, Wbeta,
                                        lng, lnb, h1, NN);

  // ---- layer 2 ----
  BiasW b2s = {{bq + HIDD, bk + HIDD, bv + HIDD, bs + HIDD}};
  gemm_qkvs<HIDD, true><<<ggrid, 256, 0, stream>>>(h1, wT + 98304, b2s, qbv, kvb, sbv, NN);
  attn_fused<<<agrid, 256, 0, stream>>>(qbv, kvu, sbv, starts, csr, Wbeta + 384,
                                        lng + HIDD, lnb + HIDD, h0, NN);

  // ---- pool + MLP ----
  hipMemsetAsync(g, 0, (size_t)NG * HIDD * 4, stream);
  hipMemsetAsync(gcnt, 0, (size_t)NG * 4, stream);
  pool_kernel<<<256, 256, 0, stream>>>(h0, batch, g, gcnt, NN);
  final_kernel<<<1, 256, 0, stream>>>(g, gcnt, mlp_W1, mlp_b1, mlp_W2, mlp_b2, outp);
}

// Round 9
// 416.123 us; speedup vs baseline: 1.4639x; 1.0719x over previous
//
#include <hip/hip_runtime.h>
#include <hip/hip_bf16.h>

#define NN 50000
#define EE 500000
#define DIN 64
#define HIDD 128
#define NG 64
#define NB1 49  // ceil(NN/1024) scan blocks

typedef short short8 __attribute__((ext_vector_type(8)));
typedef float f32x4 __attribute__((ext_vector_type(4)));

// async global->LDS, 16B per lane; LDS dest = wave-uniform base + lane*16
#define GLL(g, l)                                                              \
  __builtin_amdgcn_global_load_lds(                                            \
      (const __attribute__((address_space(1))) unsigned*)(g),                  \
      (__attribute__((address_space(3))) unsigned*)(l), 16, 0, 0)

__device__ __forceinline__ short f2bf(float f) {
  unsigned u = __float_as_uint(f);
  u += 0x7fffu + ((u >> 16) & 1u);  // RNE
  return (short)(u >> 16);
}
__device__ __forceinline__ float bfl(unsigned short u) {
  return __uint_as_float((unsigned)u << 16);
}

struct BiasW { const float* b[4]; };
struct PrepW { const float* w[8]; };  // l0 Wq,Wk,Wv,Ws then layer Wq,Wk,Wv,Ws bases

// ---------------- CSR build ----------------
__global__ __launch_bounds__(256) void count_kernel(const int* __restrict__ ei,
                                                    int* __restrict__ cnt, int E) {
  int e = blockIdx.x * 256 + threadIdx.x;
  if (e < E) atomicAdd(&cnt[ei[E + e]], 1);
}

__global__ __launch_bounds__(1024) void scan1_kernel(const int* __restrict__ cnts,
                                                     int* __restrict__ starts,
                                                     int* __restrict__ btot) {
  __shared__ int sh[1024];
  int t = threadIdx.x;
  int idx = blockIdx.x * 1024 + t;
  int v = (idx < NN) ? cnts[idx] : 0;
  sh[t] = v;
  __syncthreads();
  for (int off = 1; off < 1024; off <<= 1) {
    int add = (t >= off) ? sh[t - off] : 0;
    __syncthreads();
    sh[t] += add;
    __syncthreads();
  }
  if (idx < NN) starts[idx] = sh[t] - v;
  if (t == 1023) btot[blockIdx.x] = sh[1023];
}

__global__ __launch_bounds__(64) void scan2_kernel(const int* __restrict__ btot,
                                                   int* __restrict__ boff,
                                                   int* __restrict__ starts) {
  int t = threadIdx.x;
  int orig = (t < NB1) ? btot[t] : 0;
  int v = orig;
  for (int off = 1; off < 64; off <<= 1) {
    int n_ = __shfl_up(v, off);
    if (t >= off) v += n_;
  }
  if (t < NB1) boff[t] = v - orig;
  if (t == NB1 - 1) starts[NN] = v;
}

__global__ __launch_bounds__(256) void scan3_kernel(int* __restrict__ starts,
                                                    const int* __restrict__ boff,
                                                    int* __restrict__ pos) {
  int i = blockIdx.x * 256 + threadIdx.x;
  if (i < NN) {
    int s = starts[i] + boff[i >> 10];
    starts[i] = s;
    pos[i] = s;
  }
}

__global__ __launch_bounds__(256) void scatter_kernel(const int* __restrict__ ei,
                                                      int* __restrict__ pos,
                                                      int* __restrict__ csr_src, int E) {
  int e = blockIdx.x * 256 + threadIdx.x;
  if (e < 8) csr_src[E + e] = 0;  // zero pad so tail batches can overread safely
  if (e < E) {
    int dst = ei[E + e];
    int p = atomicAdd(&pos[dst], 1);
    csr_src[p] = ei[e];
  }
}

// ---------------- weight prep: transpose + bf16 + PRE-SWIZZLE, half-K units ----
// wT = 20 halves of 8192 shorts (16KB). Each half is [128 col][64 k], RB=128B,
// stored so a LINEAR global_load_lds copy yields the XOR-swizzled LDS image:
//   LDSbyte[col*128 + (kslot*16 ^ ((col&7)<<4)) + 2j] = W[kbase + kslot*8 + j][col]
// halves 0..3   : l0 mats q,k,v,s (K=64, one half each)
// halves 4..11  : layer-1 mats q,k,v,s (2 halves each: k 0-63, 64-127)
// halves 12..19 : layer-2 mats likewise
__global__ __launch_bounds__(256) void prep_kernel(PrepW pw, short* __restrict__ wT) {
  int o = blockIdx.x * 256 + threadIdx.x;
  if (o >= 163840) return;
  int half = o >> 13, lo = o & 8191;
  int col = lo >> 6, j = lo & 63;
  int sw = (j * 2) ^ ((col & 7) << 4);
  int kin = (sw >> 4) * 8 + ((sw & 15) >> 1);
  const float* src;
  int k;
  if (half < 4) { src = pw.w[half]; k = kin; }
  else {
    int hh = half - 4;
    int layer = hh >> 3, m = (hh >> 1) & 3, c = hh & 1;
    src = pw.w[4 + m] + layer * 16384;
    k = c * 64 + kin;
  }
  wT[o] = f2bf(src[(size_t)k * 128 + col]);
}

// ---------------- bf16 MFMA GEMM: h[N,K] x W[K,128], 4 mats fused ----------------
// 32 rows/block, 256 threads = 4 waves (2 row-groups x 2 col-halves); grid ceil(N/32).
// A-fragments DIRECT from global (registers, no LDS). B double-buffered in 2x16KB
// LDS halves via async global_load_lds from pre-swizzled wT. 2-phase pipeline.
template <int K, bool BF16IN>
__global__ __launch_bounds__(256, 5) void gemm_qkvs(
    const void* __restrict__ hin, const short* __restrict__ wT, BiasW bw,
    unsigned short* __restrict__ qb, unsigned short* __restrict__ kvb,
    unsigned short* __restrict__ sb, int N) {
  constexpr int NH = K / 64;       // halves per mat
  constexpr int NPH = 4 * NH;      // total phases
  __shared__ short bS[2][8192];    // 2 x 16KB
  const int n0 = blockIdx.x * 32;
  const int t = threadIdx.x;
  const int l = t & 63, wv = t >> 6;
  const int lr = l & 15, lk = l >> 4;
  const int rowg = wv >> 1;        // 2 row groups of 16
  const int colh = wv & 1;         // 2 col halves of 64

  // stage half 0
  {
    const char* g0 = (const char*)wT;
    char* lp = (char*)&bS[0][0];
#pragma unroll
    for (int i = 0; i < 4; ++i)
      GLL(g0 + i * 4096 + wv * 1024 + l * 16, lp + i * 4096 + wv * 1024);
  }

  // A fragments direct from global
  const int gr = n0 + rowg * 16 + lr;
  const bool ok = gr < N;
  short8 afrag[K / 32];
  if (BF16IN) {
    const short* hs = (const short*)hin;
#pragma unroll
    for (int ks = 0; ks < K / 32; ++ks) {
      short8 z = {0, 0, 0, 0, 0, 0, 0, 0};
      afrag[ks] = ok ? *(const short8*)(hs + (size_t)gr * K + ks * 32 + lk * 8) : z;
    }
  } else {
    const float* hf = (const float*)hin;
#pragma unroll
    for (int ks = 0; ks < K / 32; ++ks) {
      short8 pk = {0, 0, 0, 0, 0, 0, 0, 0};
      if (ok) {
        const float* hp = hf + (size_t)gr * K + ks * 32 + lk * 8;
        f32x4 f0 = *(const f32x4*)hp;
        f32x4 f1 = *(const f32x4*)(hp + 4);
        pk[0] = f2bf(f0.x); pk[1] = f2bf(f0.y); pk[2] = f2bf(f0.z); pk[3] = f2bf(f0.w);
        pk[4] = f2bf(f1.x); pk[5] = f2bf(f1.y); pk[6] = f2bf(f1.z); pk[7] = f2bf(f1.w);
      }
      afrag[ks] = pk;
    }
  }

#pragma unroll
  for (int mat = 0; mat < 4; ++mat) {
    f32x4 acc[4] = {};
#pragma unroll
    for (int hh = 0; hh < NH; ++hh) {
      const int g = mat * NH + hh;
      __syncthreads();  // buf[g&1] staged (drains the GLL issued last phase)
      if (g + 1 < NPH) {
        const char* gm = (const char*)(wT + (size_t)(g + 1) * 8192);
        char* lp = (char*)&bS[(g + 1) & 1][0];
#pragma unroll
        for (int i = 0; i < 4; ++i)
          GLL(gm + i * 4096 + wv * 1024 + l * 16, lp + i * 4096 + wv * 1024);
      }
      const char* bbase = (const char*)&bS[g & 1][0];
#pragma unroll
      for (int ks2 = 0; ks2 < 2; ++ks2) {
#pragma unroll
        for (int cf = 0; cf < 4; ++cf) {
          int col = colh * 64 + cf * 16 + lr;
          unsigned bb = col * 128 + (((ks2 * 4 + lk) * 16) ^ ((col & 7) << 4));
          short8 b = *(const short8*)(bbase + bb);
          acc[cf] = __builtin_amdgcn_mfma_f32_16x16x32_bf16(afrag[hh * 2 + ks2], b,
                                                            acc[cf], 0, 0, 0);
        }
      }
    }
    const float* __restrict__ bias = bw.b[mat];
#pragma unroll
    for (int cf = 0; cf < 4; ++cf) {
      int col = colh * 64 + cf * 16 + lr;
      float bv = bias[col];
#pragma unroll
      for (int r = 0; r < 4; ++r) {
        int row = n0 + rowg * 16 + lk * 4 + r;
        if (row < N) {
          unsigned short val = (unsigned short)f2bf(acc[cf][r] + bv);
          if (mat == 0) qb[(size_t)row * 128 + col] = val;
          else if (mat == 3) sb[(size_t)row * 128 + col] = val;
          else kvb[(size_t)row * 256 + (mat == 2 ? 128 : 0) + col] = val;
        }
      }
    }
  }
}

// ---------------- attention edge batch (scalarized gather base) ----------------
template <int NB, bool MASK>
__device__ __forceinline__ void att_batch(
    const int* __restrict__ csr, int i, int s1, const unsigned* __restrict__ kvu,
    int lane, float qx, float qy, float qz, float qw,
    float& d, float& ox, float& oy, float& oz, float& ow) {
  int ce = csr[i + (lane & (NB - 1))];
  uint2 w[NB];
#pragma unroll
  for (int e = 0; e < NB; ++e) {
    int s = __builtin_amdgcn_readlane(ce, e);  // wave-uniform src -> SGPR
    w[e] = *((const uint2*)kvu + ((size_t)s << 6) + lane);
  }
#pragma unroll
  for (int e = 0; e < NB; ++e) {
    float fx = __uint_as_float(w[e].x << 16);
    float fy = __uint_as_float(w[e].x & 0xffff0000u);
    float fz = __uint_as_float(w[e].y << 16);
    float fw = __uint_as_float(w[e].y & 0xffff0000u);
    float part = qx * fx + qy * fy + qz * fz + qw * fw;
    part += __shfl_xor(part, 1);
    part += __shfl_xor(part, 2);
    part += __shfl_xor(part, 4);  // head-sum over 8 lanes
    float p = __expf(part);
    if (MASK) p = (i + e < s1) ? p : 0.f;
    float pm = __shfl_xor(p, 32);  // upper half <- lower half's p
    d += p;                        // valid in lanes 0-31
    ox = fmaf(pm, fx, ox); oy = fmaf(pm, fy, oy);  // valid in lanes 32-63
    oz = fmaf(pm, fz, oz); ow = fmaf(pm, fw, ow);
  }
}

// ---------------- fused attention + beta gate + LN + GELU ----------------
__global__ __launch_bounds__(256, 8) void attn_fused(
    const unsigned short* __restrict__ qb, const unsigned* __restrict__ kvu,
    const unsigned short* __restrict__ sb, const int* __restrict__ starts,
    const int* __restrict__ csr, const float* __restrict__ Wbeta,
    const float* __restrict__ lng, const float* __restrict__ lnb,
    unsigned short* __restrict__ hout, int N) {
  int wid = (blockIdx.x * 256 + threadIdx.x) >> 6;
  if (wid >= N) return;
  const int lane = threadIdx.x & 63;
  const int cl = lane & 31;  // channel group: channels 4*cl .. 4*cl+3
  const float scale = 0.17677669529663687f;  // 1/sqrt(32)
  ushort4 qu = *(const ushort4*)&qb[(size_t)wid * 128 + 4 * cl];
  float qx = bfl(qu.x) * scale, qy = bfl(qu.y) * scale;
  float qz = bfl(qu.z) * scale, qw = bfl(qu.w) * scale;
  int s0 = starts[wid], s1 = starts[wid + 1];
  float d = 0.f, ox = 0.f, oy = 0.f, oz = 0.f, ow = 0.f;
  int i = s0;
  for (; i + 8 <= s1; i += 8)
    att_batch<8, false>(csr, i, s1, kvu, lane, qx, qy, qz, qw, d, ox, oy, oz, ow);
  if (i < s1) {
    if (s1 - i <= 4)
      att_batch<4, true>(csr, i, s1, kvu, lane, qx, qy, qz, qw, d, ox, oy, oz, ow);
    else
      att_batch<8, true>(csr, i, s1, kvu, lane, qx, qy, qz, qw, d, ox, oy, oz, ow);
  }
  float dv = __shfl_xor(d, 32);  // upper lanes: true denominator
  float inv = dv > 0.f ? 1.f / dv : 0.f;
  ox *= inv; oy *= inv; oz *= inv; ow *= inv;
  ushort4 su = *(const ushort4*)&sb[(size_t)wid * 128 + 4 * cl];
  float s_x = bfl(su.x), s_y = bfl(su.y), s_z = bfl(su.z), s_w = bfl(su.w);
  f32x4 wbo = *(const f32x4*)&Wbeta[4 * cl];
  f32x4 wbx = *(const f32x4*)&Wbeta[128 + 4 * cl];
  f32x4 wbd = *(const f32x4*)&Wbeta[256 + 4 * cl];
  float bl = ox * wbo.x + oy * wbo.y + oz * wbo.z + ow * wbo.w
           + s_x * wbx.x + s_y * wbx.y + s_z * wbx.z + s_w * wbx.w
           + (ox - s_x) * wbd.x + (oy - s_y) * wbd.y
           + (oz - s_z) * wbd.z + (ow - s_w) * wbd.w;
  bl += __shfl_xor(bl, 1);  bl += __shfl_xor(bl, 2);  bl += __shfl_xor(bl, 4);
  bl += __shfl_xor(bl, 8);  bl += __shfl_xor(bl, 16);  // sum within 32-lane half
  float beta = 1.f / (1.f + __expf(-bl));
  float hx = beta * s_x + (1.f - beta) * ox;
  float hy = beta * s_y + (1.f - beta) * oy;
  float hz = beta * s_z + (1.f - beta) * oz;
  float hw = beta * s_w + (1.f - beta) * ow;
  float s = hx + hy + hz + hw;
  float sq = hx * hx + hy * hy + hz * hz + hw * hw;
  s += __shfl_xor(s, 1);  sq += __shfl_xor(sq, 1);
  s += __shfl_xor(s, 2);  sq += __shfl_xor(sq, 2);
  s += __shfl_xor(s, 4);  sq += __shfl_xor(sq, 4);
  s += __shfl_xor(s, 8);  sq += __shfl_xor(sq, 8);
  s += __shfl_xor(s, 16); sq += __shfl_xor(sq, 16);
  float mu = s * (1.f / 128.f);
  float var = sq * (1.f / 128.f) - mu * mu;
  float rstd = 1.f / sqrtf(var + 1e-5f);
  f32x4 g4 = *(const f32x4*)&lng[4 * cl];
  f32x4 b4 = *(const f32x4*)&lnb[4 * cl];
  float y0 = (hx - mu) * rstd * g4.x + b4.x;
  float y1 = (hy - mu) * rstd * g4.y + b4.y;
  float y2 = (hz - mu) * rstd * g4.z + b4.z;
  float y3 = (hw - mu) * rstd * g4.w + b4.w;
  y0 = 0.5f * y0 * (1.f + erff(y0 * 0.70710678118654752f));
  y1 = 0.5f * y1 * (1.f + erff(y1 * 0.70710678118654752f));
  y2 = 0.5f * y2 * (1.f + erff(y2 * 0.70710678118654752f));
  y3 = 0.5f * y3 * (1.f + erff(y3 * 0.70710678118654752f));
  if (lane >= 32) {
    ushort4 o;
    o.x = (unsigned short)f2bf(y0); o.y = (unsigned short)f2bf(y1);
    o.z = (unsigned short)f2bf(y2); o.w = (unsigned short)f2bf(y3);
    *(ushort4*)&hout[(size_t)wid * 128 + 4 * cl] = o;
  }
}

// ---------------- mean pool (bf16 h input) ----------------
__global__ __launch_bounds__(256) void pool_kernel(const unsigned short* __restrict__ h,
    const int* __restrict__ batch, float* __restrict__ g,
    float* __restrict__ gcnt, int N) {
  __shared__ float accS[NG * HIDD];
  __shared__ float cntS[NG];
  int t = threadIdx.x;
  for (int i = t; i < NG * HIDD; i += 256) accS[i] = 0.f;
  if (t < NG) cntS[t] = 0.f;
  __syncthreads();
  int lane = t & 63, grp = t >> 6;
  const unsigned* h32 = (const unsigned*)h;
  for (int n = blockIdx.x * 4 + grp; n < N; n += gridDim.x * 4) {
    int b = batch[n];
    unsigned u = h32[(size_t)n * 64 + lane];
    atomicAdd(&accS[b * HIDD + (lane << 1)], __uint_as_float(u << 16));
    atomicAdd(&accS[b * HIDD + (lane << 1) + 1], __uint_as_float(u & 0xffff0000u));
    if (lane == 0) atomicAdd(&cntS[b], 1.f);
  }
  __syncthreads();
  for (int i = t; i < NG * HIDD; i += 256)
    if (accS[i] != 0.f) atomicAdd(&g[i], accS[i]);
  if (t < NG && cntS[t] != 0.f) atomicAdd(&gcnt[t], cntS[t]);
}

// ---------------- final MLP (single block) ----------------
__global__ __launch_bounds__(256) void final_kernel(const float* __restrict__ g,
    const float* __restrict__ gcnt, const float* __restrict__ W1,
    const float* __restrict__ b1, const float* __restrict__ W2,
    const float* __restrict__ b2, float* __restrict__ out) {
  __shared__ float gS[NG * HIDD];
  __shared__ float hmS[NG * HIDD];
  int t = threadIdx.x;
  for (int i = t; i < NG * HIDD; i += 256) {
    int gr = i >> 7;
    gS[i] = g[i] / fmaxf(gcnt[gr], 1.f);
  }
  __syncthreads();
  for (int i = t; i < NG * HIDD; i += 256) {
    int gr = i >> 7, col = i & 127;
    float s = b1[col];
    for (int k = 0; k < HIDD; ++k) s = fmaf(gS[gr * HIDD + k], W1[k * HIDD + col], s);
    hmS[i] = 0.5f * s * (1.f + erff(s * 0.70710678118654752f));
  }
  __syncthreads();
  if (t < NG) {
    float s = b2[0];
    for (int k = 0; k < HIDD; ++k) s = fmaf(hmS[t * HIDD + k], W2[k], s);
    out[t] = s;
  }
}

extern "C" void kernel_launch(void* const* d_in, const int* in_sizes, int n_in,
                              void* d_out, int out_size, void* d_ws, size_t ws_size,
                              hipStream_t stream) {
  const float* x        = (const float*)d_in[0];
  const int*   ei       = (const int*)d_in[1];
  const int*   batch    = (const int*)d_in[2];
  const float* l0_Wq    = (const float*)d_in[3];
  const float* l0_bq    = (const float*)d_in[4];
  const float* l0_Wk    = (const float*)d_in[5];
  const float* l0_bk    = (const float*)d_in[6];
  const float* l0_Wv    = (const float*)d_in[7];
  const float* l0_bv    = (const float*)d_in[8];
  const float* l0_Ws    = (const float*)d_in[9];
  const float* l0_bs    = (const float*)d_in[10];
  const float* l0_Wbeta = (const float*)d_in[11];
  const float* l0_lng   = (const float*)d_in[12];
  const float* l0_lnb   = (const float*)d_in[13];
  const float* Wq       = (const float*)d_in[14];
  const float* bq       = (const float*)d_in[15];
  const float* Wk       = (const float*)d_in[16];
  const float* bk       = (const float*)d_in[17];
  const float* Wv       = (const float*)d_in[18];
  const float* bv       = (const float*)d_in[19];
  const float* Ws       = (const float*)d_in[20];
  const float* bs       = (const float*)d_in[21];
  const float* Wbeta    = (const float*)d_in[22];
  const float* lng      = (const float*)d_in[23];
  const float* lnb      = (const float*)d_in[24];
  const float* mlp_W1   = (const float*)d_in[25];
  const float* mlp_b1   = (const float*)d_in[26];
  const float* mlp_W2   = (const float*)d_in[27];
  const float* mlp_b2   = (const float*)d_in[28];
  float* outp = (float*)d_out;

  char* ws = (char*)d_ws;
  size_t off = 0;
  auto alloc = [&](size_t bytes) -> void* {
    void* p = ws + off;
    off = (off + bytes + 255) & ~(size_t)255;
    return p;
  };
  unsigned short* h0  = (unsigned short*)alloc((size_t)NN * HIDD * 2);
  unsigned short* h1  = (unsigned short*)alloc((size_t)NN * HIDD * 2);
  unsigned short* qbv = (unsigned short*)alloc((size_t)NN * HIDD * 2);
  unsigned short* sbv = (unsigned short*)alloc((size_t)NN * HIDD * 2);
  unsigned short* kvb = (unsigned short*)alloc((size_t)NN * 256 * 2);
  short*  wT     = (short*)alloc((size_t)163840 * 2);
  int*    starts = (int*)alloc((size_t)(NN + 1) * 4);
  int*    pos    = (int*)alloc((size_t)NN * 4);
  int*    csr    = (int*)alloc((size_t)(EE + 8) * 4);
  int*    btot   = (int*)alloc((size_t)NB1 * 4);
  int*    boff   = (int*)alloc((size_t)NB1 * 4);
  float*  g      = (float*)alloc((size_t)NG * HIDD * 4);
  float*  gcnt   = (float*)alloc((size_t)NG * 4);
  (void)ws_size; (void)in_sizes; (void)n_in; (void)out_size;

  // ---- weight prep (transpose + bf16 + pre-swizzle, half-K units) ----
  PrepW pw = {{l0_Wq, l0_Wk, l0_Wv, l0_Ws, Wq, Wk, Wv, Ws}};
  prep_kernel<<<640, 256, 0, stream>>>(pw, wT);

  // ---- CSR build (by dst) ----
  hipMemsetAsync(pos, 0, (size_t)NN * 4, stream);
  count_kernel<<<(EE + 255) / 256, 256, 0, stream>>>(ei, pos, EE);
  scan1_kernel<<<NB1, 1024, 0, stream>>>(pos, starts, btot);
  scan2_kernel<<<1, 64, 0, stream>>>(btot, boff, starts);
  scan3_kernel<<<(NN + 255) / 256, 256, 0, stream>>>(starts, boff, pos);
  scatter_kernel<<<(EE + 255) / 256, 256, 0, stream>>>(ei, pos, csr, EE);

  int ggrid = (NN + 31) / 32;
  int agrid = (NN + 3) / 4;
  const unsigned* kvu = (const unsigned*)kvb;

  // ---- layer 0 (64 -> 128, f32 input; halves 0-3) ----
  BiasW b0 = {{l0_bq, l0_bk, l0_bv, l0_bs}};
  gemm_qkvs<DIN, false><<<ggrid, 256, 0, stream>>>(x, wT, b0, qbv, kvb, sbv, NN);
  attn_fused<<<agrid, 256, 0, stream>>>(qbv, kvu, sbv, starts, csr, l0_Wbeta,
                                        l0_lng, l0_lnb, h0, NN);

  // ---- layer 1 (halves 4-11) ----
  BiasW b1s = {{bq, bk, bv, bs}};
  gemm_qkvs<HIDD, true><<<ggrid, 256, 0, stream>>>(h0, wT + 4 * 8192, b1s, qbv, kvb, sbv, NN);
  attn_fused<<<agrid, 256, 0, stream>>>(qbv, kvu, sbv, starts, csr, Wbeta,
                                        lng, lnb, h1, NN);

  // ---- layer 2 (halves 12-19) ----
  BiasW b2s = {{bq + HIDD, bk + HIDD, bv + HIDD, bs + HIDD}};
  gemm_qkvs<HIDD, true><<<ggrid, 256, 0, stream>>>(h1, wT + 12 * 8192, b2s, qbv, kvb, sbv, NN);
  attn_fused<<<agrid, 256, 0, stream>>>(qbv, kvu, sbv, starts, csr, Wbeta + 384,
                                        lng + HIDD, lnb + HIDD, h0, NN);

  // ---- pool + MLP ----
  hipMemsetAsync(g, 0, (size_t)NG * HIDD * 4, stream);
  hipMemsetAsync(gcnt, 0, (size_t)NG * 4, stream);
  pool_kernel<<<256, 256, 0, stream>>>(h0, batch, g, gcnt, NN);
  final_kernel<<<1, 256, 0, stream>>>(g, gcnt, mlp_W1, mlp_b1, mlp_W2, mlp_b2, outp);
}

// Round 10
// 387.379 us; speedup vs baseline: 1.5725x; 1.0742x over previous
//
#include <hip/hip_runtime.h>
#include <hip/hip_bf16.h>

#define NN 50000
#define EE 500000
#define DIN 64
#define HIDD 128
#define NG 64
#define NB1 49  // ceil(NN/1024) scan blocks

typedef short short8 __attribute__((ext_vector_type(8)));
typedef float f32x4 __attribute__((ext_vector_type(4)));

// async global->LDS, 16B per lane; LDS dest = wave-uniform base + lane*16
#define GLL(g, l)                                                              \
  __builtin_amdgcn_global_load_lds(                                            \
      (const __attribute__((address_space(1))) unsigned*)(g),                  \
      (__attribute__((address_space(3))) unsigned*)(l), 16, 0, 0)

__device__ __forceinline__ short f2bf(float f) {
  unsigned u = __float_as_uint(f);
  u += 0x7fffu + ((u >> 16) & 1u);  // RNE
  return (short)(u >> 16);
}
__device__ __forceinline__ float bfl(unsigned short u) {
  return __uint_as_float((unsigned)u << 16);
}

struct BiasW { const float* b[4]; };
struct PrepW { const float* w[12]; };

// ---------------- CSR build ----------------
__global__ __launch_bounds__(256) void count_kernel(const int* __restrict__ ei,
                                                    int* __restrict__ cnt, int E) {
  int e = blockIdx.x * 256 + threadIdx.x;
  if (e < E) atomicAdd(&cnt[ei[E + e]], 1);
}

__global__ __launch_bounds__(1024) void scan1_kernel(const int* __restrict__ cnts,
                                                     int* __restrict__ starts,
                                                     int* __restrict__ btot) {
  __shared__ int sh[1024];
  int t = threadIdx.x;
  int idx = blockIdx.x * 1024 + t;
  int v = (idx < NN) ? cnts[idx] : 0;
  sh[t] = v;
  __syncthreads();
  for (int off = 1; off < 1024; off <<= 1) {
    int add = (t >= off) ? sh[t - off] : 0;
    __syncthreads();
    sh[t] += add;
    __syncthreads();
  }
  if (idx < NN) starts[idx] = sh[t] - v;
  if (t == 1023) btot[blockIdx.x] = sh[1023];
}

__global__ __launch_bounds__(64) void scan2_kernel(const int* __restrict__ btot,
                                                   int* __restrict__ boff,
                                                   int* __restrict__ starts) {
  int t = threadIdx.x;
  int orig = (t < NB1) ? btot[t] : 0;
  int v = orig;
  for (int off = 1; off < 64; off <<= 1) {
    int n_ = __shfl_up(v, off);
    if (t >= off) v += n_;
  }
  if (t < NB1) boff[t] = v - orig;
  if (t == NB1 - 1) starts[NN] = v;
}

__global__ __launch_bounds__(256) void scan3_kernel(int* __restrict__ starts,
                                                    const int* __restrict__ boff,
                                                    int* __restrict__ pos) {
  int i = blockIdx.x * 256 + threadIdx.x;
  if (i < NN) {
    int s = starts[i] + boff[i >> 10];
    starts[i] = s;
    pos[i] = s;
  }
}

__global__ __launch_bounds__(256) void scatter_kernel(const int* __restrict__ ei,
                                                      int* __restrict__ pos,
                                                      int* __restrict__ csr_src, int E) {
  int e = blockIdx.x * 256 + threadIdx.x;
  if (e < 8) csr_src[E + e] = 0;  // zero pad so tail batches can overread safely
  if (e < E) {
    int dst = ei[E + e];
    int p = atomicAdd(&pos[dst], 1);
    csr_src[p] = ei[e];
  }
}

// ---------------- weight prep: transpose + bf16 + PRE-SWIZZLE ----------------
// Stored so a LINEAR global_load_lds copy yields the XOR-swizzled LDS image:
//   LDSbyte[col*RB + (slot*16 ^ ((col&7)<<4)) + 2j] = W[slot*8+j][col]
// mats 0..3 (l0, K=64): at m*8192 shorts; mats 4..11 (K=128): at 32768+(m-4)*16384
__global__ __launch_bounds__(256) void prep_kernel(PrepW pw, short* __restrict__ wT) {
  int o = blockIdx.x * 256 + threadIdx.x;
  if (o >= 163840) return;
  int m, local, K;
  if (o < 32768) { m = o >> 13; local = o & 8191; K = 64; }
  else { int oo = o - 32768; m = 4 + (oo >> 14); local = oo & 16383; K = 128; }
  int col = local / K;
  int off = (local % K) * 2;              // byte offset within col
  int sw = off ^ ((col & 7) << 4);        // un-swizzle (XOR hits bits 4-6 only)
  int k = (sw >> 4) * 8 + ((sw & 15) >> 1);
  wT[o] = f2bf(pw.w[m][(size_t)k * 128 + col]);
}

// ---------------- mat-major persistent GEMM ----------------
// grid (GX, 4): blockIdx.y = mat. Stage the ENTIRE mat B (32KB / 16KB for l0)
// into LDS ONCE, then grid-stride over 64-row chunks (4 waves x 16-row tiles)
// with no further barriers. A-fragments direct from global.
// mat 0 -> Q, 1 -> K (kv[:,0:128]), 2 -> V (kv[:,128:256]), 3 -> S. All bf16 out.
template <int K, bool BF16IN>
__global__ __launch_bounds__(256) void gemm_mat(
    const void* __restrict__ hin, const short* __restrict__ wT, BiasW bw,
    unsigned short* __restrict__ qb, unsigned short* __restrict__ kvb,
    unsigned short* __restrict__ sb, int N) {
  constexpr int RB = 2 * K;
  constexpr int CALLS = (128 * RB) / 4096;  // 8 (K=128) or 4 (K=64)
  __shared__ short bS[128 * K];
  const int mat = blockIdx.y;
  const short* __restrict__ wm = wT + (size_t)mat * 128 * K;
  const int t = threadIdx.x, l = t & 63, wv = t >> 6;

  {
    const char* g0 = (const char*)wm;
    char* lp = (char*)bS;
#pragma unroll
    for (int i = 0; i < CALLS; ++i)
      GLL(g0 + i * 4096 + wv * 1024 + l * 16, lp + i * 4096 + wv * 1024);
  }
  __syncthreads();  // B resident for the whole kernel

  const int lr = l & 15, lk = l >> 4;
  const float* __restrict__ bias = bw.b[mat];
  unsigned short* outp;
  int ostride;
  if (mat == 0) { outp = qb; ostride = 128; }
  else if (mat == 1) { outp = kvb; ostride = 256; }
  else if (mat == 2) { outp = kvb + 128; ostride = 256; }
  else { outp = sb; ostride = 128; }

  for (int r0 = blockIdx.x * 64 + wv * 16; r0 < N; r0 += gridDim.x * 64) {
    const int gr = r0 + lr;
    const bool ok = gr < N;
    short8 afrag[K / 32];
    if (BF16IN) {
      const short* hs = (const short*)hin;
#pragma unroll
      for (int ks = 0; ks < K / 32; ++ks) {
        short8 z = {0, 0, 0, 0, 0, 0, 0, 0};
        afrag[ks] = ok ? *(const short8*)(hs + (size_t)gr * K + ks * 32 + lk * 8) : z;
      }
    } else {
      const float* hf = (const float*)hin;
#pragma unroll
      for (int ks = 0; ks < K / 32; ++ks) {
        short8 pk = {0, 0, 0, 0, 0, 0, 0, 0};
        if (ok) {
          const float* hp = hf + (size_t)gr * K + ks * 32 + lk * 8;
          f32x4 f0 = *(const f32x4*)hp;
          f32x4 f1 = *(const f32x4*)(hp + 4);
          pk[0] = f2bf(f0.x); pk[1] = f2bf(f0.y); pk[2] = f2bf(f0.z); pk[3] = f2bf(f0.w);
          pk[4] = f2bf(f1.x); pk[5] = f2bf(f1.y); pk[6] = f2bf(f1.z); pk[7] = f2bf(f1.w);
        }
        afrag[ks] = pk;
      }
    }

    f32x4 acc[8] = {};
#pragma unroll
    for (int ks = 0; ks < K / 32; ++ks) {
#pragma unroll
      for (int cf = 0; cf < 8; ++cf) {
        int col = cf * 16 + lr;
        unsigned bb = col * RB + ((((ks * 4 + lk) * 16)) ^ ((col & 7) << 4));
        short8 b = *(const short8*)((const char*)bS + bb);
        acc[cf] = __builtin_amdgcn_mfma_f32_16x16x32_bf16(afrag[ks], b, acc[cf], 0, 0, 0);
      }
    }

#pragma unroll
    for (int cf = 0; cf < 8; ++cf) {
      int col = cf * 16 + lr;
      float bv = bias[col];
#pragma unroll
      for (int r = 0; r < 4; ++r) {
        int row = r0 + lk * 4 + r;
        if (row < N)
          outp[(size_t)row * ostride + col] = (unsigned short)f2bf(acc[cf][r] + bv);
      }
    }
  }
}

// ---------------- attention edge batch (scalarized gather base) ----------------
template <int NB, bool MASK>
__device__ __forceinline__ void att_batch(
    const int* __restrict__ csr, int i, int s1, const unsigned* __restrict__ kvu,
    int lane, float qx, float qy, float qz, float qw,
    float& d, float& ox, float& oy, float& oz, float& ow) {
  int ce = csr[i + (lane & (NB - 1))];
  uint2 w[NB];
#pragma unroll
  for (int e = 0; e < NB; ++e) {
    int s = __builtin_amdgcn_readlane(ce, e);  // wave-uniform src -> SGPR
    w[e] = *((const uint2*)kvu + ((size_t)s << 6) + lane);
  }
#pragma unroll
  for (int e = 0; e < NB; ++e) {
    float fx = __uint_as_float(w[e].x << 16);
    float fy = __uint_as_float(w[e].x & 0xffff0000u);
    float fz = __uint_as_float(w[e].y << 16);
    float fw = __uint_as_float(w[e].y & 0xffff0000u);
    float part = qx * fx + qy * fy + qz * fz + qw * fw;
    part += __shfl_xor(part, 1);
    part += __shfl_xor(part, 2);
    part += __shfl_xor(part, 4);  // head-sum over 8 lanes
    float p = __expf(part);
    if (MASK) p = (i + e < s1) ? p : 0.f;
    float pm = __shfl_xor(p, 32);  // upper half <- lower half's p
    d += p;                        // valid in lanes 0-31
    ox = fmaf(pm, fx, ox); oy = fmaf(pm, fy, oy);  // valid in lanes 32-63
    oz = fmaf(pm, fz, oz); ow = fmaf(pm, fw, ow);
  }
}

// ---------------- fused attention + beta gate + LN + GELU ----------------
__global__ __launch_bounds__(256, 8) void attn_fused(
    const unsigned short* __restrict__ qb, const unsigned* __restrict__ kvu,
    const unsigned short* __restrict__ sb, const int* __restrict__ starts,
    const int* __restrict__ csr, const float* __restrict__ Wbeta,
    const float* __restrict__ lng, const float* __restrict__ lnb,
    unsigned short* __restrict__ hout, int N) {
  int wid = (blockIdx.x * 256 + threadIdx.x) >> 6;
  if (wid >= N) return;
  const int lane = threadIdx.x & 63;
  const int cl = lane & 31;  // channel group: channels 4*cl .. 4*cl+3
  const float scale = 0.17677669529663687f;  // 1/sqrt(32)
  ushort4 qu = *(const ushort4*)&qb[(size_t)wid * 128 + 4 * cl];
  float qx = bfl(qu.x) * scale, qy = bfl(qu.y) * scale;
  float qz = bfl(qu.z) * scale, qw = bfl(qu.w) * scale;
  int s0 = starts[wid], s1 = starts[wid + 1];
  float d = 0.f, ox = 0.f, oy = 0.f, oz = 0.f, ow = 0.f;
  int i = s0;
  for (; i + 8 <= s1; i += 8)
    att_batch<8, false>(csr, i, s1, kvu, lane, qx, qy, qz, qw, d, ox, oy, oz, ow);
  if (i < s1) {
    if (s1 - i <= 4)
      att_batch<4, true>(csr, i, s1, kvu, lane, qx, qy, qz, qw, d, ox, oy, oz, ow);
    else
      att_batch<8, true>(csr, i, s1, kvu, lane, qx, qy, qz, qw, d, ox, oy, oz, ow);
  }
  float dv = __shfl_xor(d, 32);  // upper lanes: true denominator
  float inv = dv > 0.f ? 1.f / dv : 0.f;
  ox *= inv; oy *= inv; oz *= inv; ow *= inv;
  ushort4 su = *(const ushort4*)&sb[(size_t)wid * 128 + 4 * cl];
  float s_x = bfl(su.x), s_y = bfl(su.y), s_z = bfl(su.z), s_w = bfl(su.w);
  f32x4 wbo = *(const f32x4*)&Wbeta[4 * cl];
  f32x4 wbx = *(const f32x4*)&Wbeta[128 + 4 * cl];
  f32x4 wbd = *(const f32x4*)&Wbeta[256 + 4 * cl];
  float bl = ox * wbo.x + oy * wbo.y + oz * wbo.z + ow * wbo.w
           + s_x * wbx.x + s_y * wbx.y + s_z * wbx.z + s_w * wbx.w
           + (ox - s_x) * wbd.x + (oy - s_y) * wbd.y
           + (oz - s_z) * wbd.z + (ow - s_w) * wbd.w;
  bl += __shfl_xor(bl, 1);  bl += __shfl_xor(bl, 2);  bl += __shfl_xor(bl, 4);
  bl += __shfl_xor(bl, 8);  bl += __shfl_xor(bl, 16);  // sum within 32-lane half
  float beta = 1.f / (1.f + __expf(-bl));
  float hx = beta * s_x + (1.f - beta) * ox;
  float hy = beta * s_y + (1.f - beta) * oy;
  float hz = beta * s_z + (1.f - beta) * oz;
  float hw = beta * s_w + (1.f - beta) * ow;
  float s = hx + hy + hz + hw;
  float sq = hx * hx + hy * hy + hz * hz + hw * hw;
  s += __shfl_xor(s, 1);  sq += __shfl_xor(sq, 1);
  s += __shfl_xor(s, 2);  sq += __shfl_xor(sq, 2);
  s += __shfl_xor(s, 4);  sq += __shfl_xor(sq, 4);
  s += __shfl_xor(s, 8);  sq += __shfl_xor(sq, 8);
  s += __shfl_xor(s, 16); sq += __shfl_xor(sq, 16);
  float mu = s * (1.f / 128.f);
  float var = sq * (1.f / 128.f) - mu * mu;
  float rstd = 1.f / sqrtf(var + 1e-5f);
  f32x4 g4 = *(const f32x4*)&lng[4 * cl];
  f32x4 b4 = *(const f32x4*)&lnb[4 * cl];
  float y0 = (hx - mu) * rstd * g4.x + b4.x;
  float y1 = (hy - mu) * rstd * g4.y + b4.y;
  float y2 = (hz - mu) * rstd * g4.z + b4.z;
  float y3 = (hw - mu) * rstd * g4.w + b4.w;
  y0 = 0.5f * y0 * (1.f + erff(y0 * 0.70710678118654752f));
  y1 = 0.5f * y1 * (1.f + erff(y1 * 0.70710678118654752f));
  y2 = 0.5f * y2 * (1.f + erff(y2 * 0.70710678118654752f));
  y3 = 0.5f * y3 * (1.f + erff(y3 * 0.70710678118654752f));
  if (lane >= 32) {
    ushort4 o;
    o.x = (unsigned short)f2bf(y0); o.y = (unsigned short)f2bf(y1);
    o.z = (unsigned short)f2bf(y2); o.w = (unsigned short)f2bf(y3);
    *(ushort4*)&hout[(size_t)wid * 128 + 4 * cl] = o;
  }
}

// ---------------- mean pool (bf16 h input) ----------------
__global__ __launch_bounds__(256) void pool_kernel(const unsigned short* __restrict__ h,
    const int* __restrict__ batch, float* __restrict__ g,
    float* __restrict__ gcnt, int N) {
  __shared__ float accS[NG * HIDD];
  __shared__ float cntS[NG];
  int t = threadIdx.x;
  for (int i = t; i < NG * HIDD; i += 256) accS[i] = 0.f;
  if (t < NG) cntS[t] = 0.f;
  __syncthreads();
  int lane = t & 63, grp = t >> 6;
  const unsigned* h32 = (const unsigned*)h;
  for (int n = blockIdx.x * 4 + grp; n < N; n += gridDim.x * 4) {
    int b = batch[n];
    unsigned u = h32[(size_t)n * 64 + lane];
    atomicAdd(&accS[b * HIDD + (lane << 1)], __uint_as_float(u << 16));
    atomicAdd(&accS[b * HIDD + (lane << 1) + 1], __uint_as_float(u & 0xffff0000u));
    if (lane == 0) atomicAdd(&cntS[b], 1.f);
  }
  __syncthreads();
  for (int i = t; i < NG * HIDD; i += 256)
    if (accS[i] != 0.f) atomicAdd(&g[i], accS[i]);
  if (t < NG && cntS[t] != 0.f) atomicAdd(&gcnt[t], cntS[t]);
}

// ---------------- final MLP (single block) ----------------
__global__ __launch_bounds__(256) void final_kernel(const float* __restrict__ g,
    const float* __restrict__ gcnt, const float* __restrict__ W1,
    const float* __restrict__ b1, const float* __restrict__ W2,
    const float* __restrict__ b2, float* __restrict__ out) {
  __shared__ float gS[NG * HIDD];
  __shared__ float hmS[NG * HIDD];
  int t = threadIdx.x;
  for (int i = t; i < NG * HIDD; i += 256) {
    int gr = i >> 7;
    gS[i] = g[i] / fmaxf(gcnt[gr], 1.f);
  }
  __syncthreads();
  for (int i = t; i < NG * HIDD; i += 256) {
    int gr = i >> 7, col = i & 127;
    float s = b1[col];
    for (int k = 0; k < HIDD; ++k) s = fmaf(gS[gr * HIDD + k], W1[k * HIDD + col], s);
    hmS[i] = 0.5f * s * (1.f + erff(s * 0.70710678118654752f));
  }
  __syncthreads();
  if (t < NG) {
    float s = b2[0];
    for (int k = 0; k < HIDD; ++k) s = fmaf(hmS[t * HIDD + k], W2[k], s);
    out[t] = s;
  }
}

extern "C" void kernel_launch(void* const* d_in, const int* in_sizes, int n_in,
                              void* d_out, int out_size, void* d_ws, size_t ws_size,
                              hipStream_t stream) {
  const float* x        = (const float*)d_in[0];
  const int*   ei       = (const int*)d_in[1];
  const int*   batch    = (const int*)d_in[2];
  const float* l0_Wq    = (const float*)d_in[3];
  const float* l0_bq    = (const float*)d_in[4];
  const float* l0_Wk    = (const float*)d_in[5];
  const float* l0_bk    = (const float*)d_in[6];
  const float* l0_Wv    = (const float*)d_in[7];
  const float* l0_bv    = (const float*)d_in[8];
  const float* l0_Ws    = (const float*)d_in[9];
  const float* l0_bs    = (const float*)d_in[10];
  const float* l0_Wbeta = (const float*)d_in[11];
  const float* l0_lng   = (const float*)d_in[12];
  const float* l0_lnb   = (const float*)d_in[13];
  const float* Wq       = (const float*)d_in[14];
  const float* bq       = (const float*)d_in[15];
  const float* Wk       = (const float*)d_in[16];
  const float* bk       = (const float*)d_in[17];
  const float* Wv       = (const float*)d_in[18];
  const float* bv       = (const float*)d_in[19];
  const float* Ws       = (const float*)d_in[20];
  const float* bs       = (const float*)d_in[21];
  const float* Wbeta    = (const float*)d_in[22];
  const float* lng      = (const float*)d_in[23];
  const float* lnb      = (const float*)d_in[24];
  const float* mlp_W1   = (const float*)d_in[25];
  const float* mlp_b1   = (const float*)d_in[26];
  const float* mlp_W2   = (const float*)d_in[27];
  const float* mlp_b2   = (const float*)d_in[28];
  float* outp = (float*)d_out;

  char* ws = (char*)d_ws;
  size_t off = 0;
  auto alloc = [&](size_t bytes) -> void* {
    void* p = ws + off;
    off = (off + bytes + 255) & ~(size_t)255;
    return p;
  };
  unsigned short* h0  = (unsigned short*)alloc((size_t)NN * HIDD * 2);
  unsigned short* h1  = (unsigned short*)alloc((size_t)NN * HIDD * 2);
  unsigned short* qbv = (unsigned short*)alloc((size_t)NN * HIDD * 2);
  unsigned short* sbv = (unsigned short*)alloc((size_t)NN * HIDD * 2);
  unsigned short* kvb = (unsigned short*)alloc((size_t)NN * 256 * 2);
  short*  wT     = (short*)alloc((size_t)163840 * 2);
  int*    starts = (int*)alloc((size_t)(NN + 1) * 4);
  int*    pos    = (int*)alloc((size_t)NN * 4);
  int*    csr    = (int*)alloc((size_t)(EE + 8) * 4);
  int*    btot   = (int*)alloc((size_t)NB1 * 4);
  int*    boff   = (int*)alloc((size_t)NB1 * 4);
  float*  g      = (float*)alloc((size_t)NG * HIDD * 4);
  float*  gcnt   = (float*)alloc((size_t)NG * 4);
  (void)ws_size; (void)in_sizes; (void)n_in; (void)out_size;

  // ---- weight prep (transpose + bf16 + pre-swizzle) ----
  PrepW pw = {{l0_Wq, l0_Wk, l0_Wv, l0_Ws,
               Wq, Wk, Wv, Ws,
               Wq + 16384, Wk + 16384, Wv + 16384, Ws + 16384}};
  prep_kernel<<<640, 256, 0, stream>>>(pw, wT);

  // ---- CSR build (by dst) ----
  hipMemsetAsync(pos, 0, (size_t)NN * 4, stream);
  count_kernel<<<(EE + 255) / 256, 256, 0, stream>>>(ei, pos, EE);
  scan1_kernel<<<NB1, 1024, 0, stream>>>(pos, starts, btot);
  scan2_kernel<<<1, 64, 0, stream>>>(btot, boff, starts);
  scan3_kernel<<<(NN + 255) / 256, 256, 0, stream>>>(starts, boff, pos);
  scatter_kernel<<<(EE + 255) / 256, 256, 0, stream>>>(ei, pos, csr, EE);

  dim3 ggrid(256, 4);
  int agrid = (NN + 3) / 4;
  const unsigned* kvu = (const unsigned*)kvb;

  // ---- layer 0 (64 -> 128, f32 input; mats at wT) ----
  BiasW b0 = {{l0_bq, l0_bk, l0_bv, l0_bs}};
  gemm_mat<DIN, false><<<ggrid, 256, 0, stream>>>(x, wT, b0, qbv, kvb, sbv, NN);
  attn_fused<<<agrid, 256, 0, stream>>>(qbv, kvu, sbv, starts, csr, l0_Wbeta,
                                        l0_lng, l0_lnb, h0, NN);

  // ---- layer 1 (mats at wT+32768) ----
  BiasW b1s = {{bq, bk, bv, bs}};
  gemm_mat<HIDD, true><<<ggrid, 256, 0, stream>>>(h0, wT + 32768, b1s, qbv, kvb, sbv, NN);
  attn_fused<<<agrid, 256, 0, stream>>>(qbv, kvu, sbv, starts, csr, Wbeta,
                                        lng, lnb, h1, NN);

  // ---- layer 2 (mats at wT+98304) ----
  BiasW b2s = {{bq + HIDD, bk + HIDD, bv + HIDD, bs + HIDD}};
  gemm_mat<HIDD, true><<<ggrid, 256, 0, stream>>>(h1, wT + 98304, b2s, qbv, kvb, sbv, NN);
  attn_fused<<<agrid, 256, 0, stream>>>(qbv, kvu, sbv, starts, csr, Wbeta + 384,
                                        lng + HIDD, lnb + HIDD, h0, NN);

  // ---- pool + MLP ----
  hipMemsetAsync(g, 0, (size_t)NG * HIDD * 4, stream);
  hipMemsetAsync(gcnt, 0, (size_t)NG * 4, stream);
  pool_kernel<<<256, 256, 0, stream>>>(h0, batch, g, gcnt, NN);
  final_kernel<<<1, 256, 0, stream>>>(g, gcnt, mlp_W1, mlp_b1, mlp_W2, mlp_b2, outp);
}